// Round 11
// baseline (564.186 us; speedup 1.0000x reference)
//
#include <hip/hip_runtime.h>
#include <hip/hip_bf16.h>

// Problem constants
#define T_TOK 4096          // B*S tokens
#define D_DIM 1024
#define H_DIM 4096
#define E_EXP 8
#define K_TOP 2
#define TP (T_TOK * K_TOP)  // 8192 (token, expert) pairs
#define BM 128
#define BN 128
#define BKS 32              // K-step (shorts) -- r2/r5-verified
#define MAX_TILES 72

typedef __attribute__((ext_vector_type(8))) short bf16x8;
typedef __attribute__((ext_vector_type(4))) float f32x4;
typedef __attribute__((ext_vector_type(8))) unsigned short u16x8;
typedef __attribute__((ext_vector_type(4))) unsigned short u16x4;

// LDS chunk swizzle: permute the four 16B chunks within a row's 64B slab.
// Applied identically on the global source column (same 64B segment ->
// coalescing unchanged) and on the LDS fragment read.
// Verified r2/r5/r6/r8/r10: SQ_LDS_BANK_CONFLICT == 0.
#define SWZ(row, chunk) ((chunk) ^ (((row) >> 1) & 3))

static __device__ __forceinline__ void gload16(const unsigned short* g, unsigned short* l) {
  // async global->LDS, 16B per lane; LDS dest = wave-uniform base + lane*16
  __builtin_amdgcn_global_load_lds((const __attribute__((address_space(1))) void*)g,
                                   (__attribute__((address_space(3))) void*)l, 16, 0, 0);
}

static __device__ __forceinline__ unsigned short f2bf(float f) {
  // round-to-nearest-even fp32 -> bf16
  unsigned int bits = __float_as_uint(f);
  unsigned int lsb = (bits >> 16) & 1u;
  bits += 0x7fffu + lsb;
  return (unsigned short)(bits >> 16);
}

static __device__ __forceinline__ float gelu_fast(float u) {
  // tanh-form gelu: u * sigmoid(1.5957691 * (u + 0.044715 u^3)); |err| <~ 3e-4
  float z = u * (0.79788456080286536f + 0.0356774081f * u * u);
  float t = __expf(-2.f * z);
  return u / (1.f + t);
}

// ---------------- transpose + convert: src [E][R][C] fp32 -> dst [E][C][R] bf16 ----------------
// r8-verified: 64x64 tiles; float4 reads; fp32 LDS [64][65]; u16x8 writes.
__global__ __launch_bounds__(256) void transpose_bf16_kernel(
    const float* __restrict__ src, unsigned short* __restrict__ dst, int R, int C) {
  __shared__ float tile[64][65];
  const int e = blockIdx.z;
  const int c0 = blockIdx.x * 64, r0 = blockIdx.y * 64;
  const int tid = threadIdx.x;
  const float* s = src + (size_t)e * R * C;
  unsigned short* d = dst + (size_t)e * R * C;

  // read: 64 rows x 16 float4; lane (row=tid>>4, c4=tid&15), 4 passes
  const int rr = tid >> 4, c4 = tid & 15;
#pragma unroll
  for (int p = 0; p < 4; ++p) {
    int r = rr + p * 16;
    float4 v = *(const float4*)(&s[(size_t)(r0 + r) * C + c0 + c4 * 4]);
    tile[r][c4 * 4 + 0] = v.x;
    tile[r][c4 * 4 + 1] = v.y;
    tile[r][c4 * 4 + 2] = v.z;
    tile[r][c4 * 4 + 3] = v.w;
  }
  __syncthreads();
  // write: out row c (64 bf16 = 128B); lane (c=tid>>3, r8=tid&7), 2 passes
  const int cc = tid >> 3, r8 = tid & 7;
#pragma unroll
  for (int p = 0; p < 2; ++p) {
    int c = cc + p * 32;
    u16x8 o;
#pragma unroll
    for (int q = 0; q < 8; ++q) o[q] = f2bf(tile[r8 * 8 + q][c]);
    *(u16x8*)(&d[(size_t)(c0 + c) * R + r0 + r8 * 8]) = o;
  }
}

// ---------------- gating: fp32 exact, one wave per token ----------------
// r9-verified: also emits xb (bf16 copy of x) -- fuses the former convert_x kernel.
__global__ __launch_bounds__(256) void gating_kernel(
    const float* __restrict__ x, const float* __restrict__ noise,
    const float* __restrict__ Wg, const float* __restrict__ bg,
    const float* __restrict__ Wn, const float* __restrict__ bn,
    int* __restrict__ tok_e, float* __restrict__ tok_w,
    float* __restrict__ gp_tok, int* __restrict__ counts,
    unsigned short* __restrict__ xb) {
  const int tid = threadIdx.x, lane = tid & 63, wid = tid >> 6;
  const int t = blockIdx.x * 4 + wid;
  const float* xrow = x + (size_t)t * D_DIM;
  float ag[8] = {0, 0, 0, 0, 0, 0, 0, 0};
  float an[8] = {0, 0, 0, 0, 0, 0, 0, 0};
#pragma unroll 4
  for (int i = 0; i < 16; ++i) {
    int dd = i * 64 + lane;
    float xv = xrow[dd];
    xb[(size_t)t * D_DIM + dd] = f2bf(xv);          // fused x -> bf16 (coalesced 128B/wave)
    const float4* g4 = (const float4*)(Wg + (size_t)dd * 8);
    const float4* n4 = (const float4*)(Wn + (size_t)dd * 8);
    float4 ga = g4[0], gb = g4[1], na = n4[0], nb = n4[1];
    ag[0] += xv * ga.x; ag[1] += xv * ga.y; ag[2] += xv * ga.z; ag[3] += xv * ga.w;
    ag[4] += xv * gb.x; ag[5] += xv * gb.y; ag[6] += xv * gb.z; ag[7] += xv * gb.w;
    an[0] += xv * na.x; an[1] += xv * na.y; an[2] += xv * na.z; an[3] += xv * na.w;
    an[4] += xv * nb.x; an[5] += xv * nb.y; an[6] += xv * nb.z; an[7] += xv * nb.w;
  }
#pragma unroll
  for (int e = 0; e < 8; ++e) {
    for (int off = 32; off > 0; off >>= 1) {
      ag[e] += __shfl_down(ag[e], off);
      an[e] += __shfl_down(an[e], off);
    }
  }
  if (lane == 0) {
    float logit[8], noisy[8];
#pragma unroll
    for (int e = 0; e < 8; ++e) {
      logit[e] = ag[e] + bg[e];
      float pre = an[e] + bn[e];
      float sp = fmaxf(pre, 0.f) + log1pf(expf(-fabsf(pre)));   // softplus, stable
      noisy[e] = logit[e] + noise[(size_t)t * 8 + e] * sp;
    }
    // clean-gate softmax for load loss
    float mx = logit[0];
#pragma unroll
    for (int e = 1; e < 8; ++e) mx = fmaxf(mx, logit[e]);
    float s = 0.f, p[8];
#pragma unroll
    for (int e = 0; e < 8; ++e) { p[e] = expf(logit[e] - mx); s += p[e]; }
    float inv = 1.f / s;
#pragma unroll
    for (int e = 0; e < 8; ++e) gp_tok[(size_t)t * 8 + e] = p[e] * inv;
    // top-2 (strict > keeps lowest index on ties, matching lax.top_k)
    int i0 = 0; float v0 = noisy[0];
#pragma unroll
    for (int e = 1; e < 8; ++e) if (noisy[e] > v0) { v0 = noisy[e]; i0 = e; }
    int i1 = -1; float v1 = 0.f;
#pragma unroll
    for (int e = 0; e < 8; ++e) {
      if (e == i0) continue;
      if (i1 < 0 || noisy[e] > v1) { v1 = noisy[e]; i1 = e; }
    }
    float e1 = expf(v1 - v0);        // v0 >= v1
    float w0 = 1.f / (1.f + e1);
    float w1 = e1 * w0;
    tok_e[t * 2 + 0] = i0; tok_e[t * 2 + 1] = i1;
    tok_w[t * 2 + 0] = w0; tok_w[t * 2 + 1] = w1;
    atomicAdd(&counts[i0], 1);
    atomicAdd(&counts[i1], 1);
  }
}

// ---------------- scan: offsets + tile table (1 thread, trivial) ----------------
__global__ void scan_kernel(const int* __restrict__ counts, int* __restrict__ offsets,
                            int* __restrict__ cursor, int4* __restrict__ tiles,
                            int* __restrict__ ntiles) {
  if (threadIdx.x == 0 && blockIdx.x == 0) {
    int off = 0, nt = 0;
    for (int e = 0; e < E_EXP; ++e) {
      offsets[e] = off;
      int c = counts[e];
      for (int r = 0; r < c; r += BM) {
        tiles[nt] = make_int4(e, off + r, min(BM, c - r), 0);
        ++nt;
      }
      off += c;
      cursor[e] = 0;
    }
    offsets[E_EXP] = off;
    *ntiles = nt;
  }
}

// ---------------- scatter tokens into compact per-expert pair lists ----------------
__global__ __launch_bounds__(256) void scatter_kernel(
    const int* __restrict__ tok_e, const float* __restrict__ tok_w,
    const int* __restrict__ offsets, int* __restrict__ cursor,
    int* __restrict__ pair_token, float* __restrict__ pair_w) {
  int t = blockIdx.x * 256 + threadIdx.x;
  if (t >= T_TOK) return;
#pragma unroll
  for (int k = 0; k < 2; ++k) {
    int e = tok_e[t * 2 + k];
    int pos = atomicAdd(&cursor[e], 1);
    int p = offsets[e] + pos;
    pair_token[p] = t;
    pair_w[p] = tok_w[t * 2 + k];
  }
}

// ---------------- FFN1: h = gelu(X_e @ W1_e + b1_e), grouped GEMM, bf16 MFMA ----------------
// r6/r8/r10-verified: counted vmcnt(4) depth-2 pipeline + coalesced LDS epilogue.
__global__ __launch_bounds__(256) void ffn1_kernel(
    const unsigned short* __restrict__ xb,    // [T][D] bf16
    const unsigned short* __restrict__ w1t,   // [E][H][D] bf16 (transposed)
    const float* __restrict__ b1,             // [E][H]
    const int* __restrict__ pair_token,       // [TP]
    const int4* __restrict__ tiles, const int* __restrict__ ntiles,
    unsigned short* __restrict__ hbuf) {      // [TP][H] bf16
  const int NB = H_DIM / BN;                  // 32
  const int nwg = MAX_TILES * NB;             // 2304, %8==0
  int bid = blockIdx.x;
  int wg = (bid & 7) * (nwg >> 3) + (bid >> 3);   // bijective XCD chunking
  int tileId = wg / NB, nb = wg - tileId * NB;    // tile-major within an XCD
  if (tileId >= *ntiles) return;
  int4 tl = tiles[tileId];
  const int e = tl.x, row0 = tl.y, rows = tl.z;
  const int n0 = nb * BN;

  __shared__ unsigned short sh[16384];        // 32KB: As(2x8KB)+Bs(2x8KB); reused as [128][128] epilogue tile
#define AS1(buf) (sh + (buf) * 4096)
#define BS1(buf) (sh + 8192 + (buf) * 4096)

  const int tid = threadIdx.x;
  const int wid = tid >> 6, lane = tid & 63;
  const int sr = tid >> 2;                    // local row 0..63 (and +64)
  const int sc = tid & 3;                     // 16B chunk 0..3
  const int scz = SWZ(sr, sc) * 8;            // swizzled source column (shorts)

  int r0a = row0 + sr;       if (r0a > TP - 1) r0a = TP - 1;
  int r1a = row0 + sr + 64;  if (r1a > TP - 1) r1a = TP - 1;
  const unsigned short* a0 = xb + (size_t)pair_token[r0a] * D_DIM + scz;
  const unsigned short* a1 = xb + (size_t)pair_token[r1a] * D_DIM + scz;
  const unsigned short* bp0 = w1t + ((size_t)e * H_DIM + (n0 + sr)) * D_DIM + scz;
  const unsigned short* bp1 = w1t + ((size_t)e * H_DIM + (n0 + sr + 64)) * D_DIM + scz;

  const int wbase = wid * 512;                // wave-uniform LDS offset (shorts)
  const int wr = wid >> 1, wc = wid & 1;
  const int lrow = lane & 15, lkc = lane >> 4;  // fragment chunk 0..3

  f32x4 acc[4][4] = {};

  auto stage = [&](int buf, int k0) {         // exactly 4 VMEM ops per wave
    gload16(a0 + k0, AS1(buf) + wbase);
    gload16(a1 + k0, AS1(buf) + wbase + 2048);
    gload16(bp0 + k0, BS1(buf) + wbase);
    gload16(bp1 + k0, BS1(buf) + wbase + 2048);
  };
  auto compute_step = [&](int buf) {
    bf16x8 af[4], bfr[4];
#pragma unroll
    for (int m = 0; m < 4; ++m) {
      int r = wr * 64 + m * 16 + lrow;
      af[m] = *(const bf16x8*)(AS1(buf) + r * BKS + SWZ(r, lkc) * 8);
    }
#pragma unroll
    for (int n = 0; n < 4; ++n) {
      int r = wc * 64 + n * 16 + lrow;
      bfr[n] = *(const bf16x8*)(BS1(buf) + r * BKS + SWZ(r, lkc) * 8);
    }
#pragma unroll
    for (int m = 0; m < 4; ++m)
#pragma unroll
      for (int n = 0; n < 4; ++n)
        acc[m][n] = __builtin_amdgcn_mfma_f32_16x16x32_bf16(af[m], bfr[n], acc[m][n], 0, 0, 0);
  };

  const int NK = D_DIM / BKS;                 // 32
  stage(0, 0);
  stage(1, BKS);
  int cur = 0;
  for (int k = 0; k < NK - 1; ++k) {
    asm volatile("s_waitcnt vmcnt(4)" ::: "memory");  // cur's 4 loads done; next 4 in flight
    __builtin_amdgcn_s_barrier();
    __builtin_amdgcn_sched_barrier(0);        // pin ds_reads after barrier
    compute_step(cur);
    __builtin_amdgcn_sched_barrier(0);
    __builtin_amdgcn_s_barrier();             // all reads of buf[cur] retired
    if (k < NK - 2) stage(cur, (k + 2) * BKS);  // refill (uniform branch)
    cur ^= 1;
  }
  asm volatile("s_waitcnt vmcnt(0)" ::: "memory");
  __builtin_amdgcn_s_barrier();
  __builtin_amdgcn_sched_barrier(0);
  compute_step(cur);

  // ---- epilogue: gelu -> LDS [128][128] (chunk-XOR swizzled) -> coalesced stores ----
  __syncthreads();                            // everyone done reading staging LDS
#pragma unroll
  for (int n = 0; n < 4; ++n) {
    int clocal = wc * 64 + n * 16 + lrow;
    float bias = b1[(size_t)e * H_DIM + n0 + clocal];
    int chunk = clocal >> 3, within = clocal & 7;
#pragma unroll
    for (int m = 0; m < 4; ++m) {
#pragma unroll
      for (int j = 0; j < 4; ++j) {
        int rloc = wr * 64 + m * 16 + (lane >> 4) * 4 + j;
        float v = acc[m][n][j] + bias;
        sh[rloc * 128 + ((chunk ^ ((rloc >> 1) & 7)) * 8) + within] = f2bf(gelu_fast(v));
      }
    }
  }
  __syncthreads();
#pragma unroll
  for (int it = 0; it < 8; ++it) {
    int u = tid + 256 * it;                   // 0..2047: row = u>>4, 16B-chunk = u&15
    int r = u >> 4, cg = u & 15;
    if (r < rows) {
      u16x8 v = *(const u16x8*)(&sh[r * 128 + ((cg ^ ((r >> 1) & 7)) * 8)]);
      *(u16x8*)(&hbuf[(size_t)(row0 + r) * H_DIM + n0 + cg * 8]) = v;  // 256B runs/row
    }
  }
#undef AS1
#undef BS1
}

// ---------------- FFN2: out[token] += w * (h_e @ W2_e + b2_e) ----------------
// r11: intra-block split-K -- 512 threads, two 4-wave groups; group g owns
// K-range [g*2048, (g+1)*2048) with its own LDS region and the r8-verified
// counted-vmcnt(4) depth-2 pipeline. Raises waves/CU 9->16 with ZERO extra
// HBM fetch (each group reads its own K-half) and unchanged per-step
// arithmetic intensity. Block-wide barriers stay lockstep (both groups run
// identical loop counts). 4 atomic adds/output elem (2 experts x 2 groups).
__global__ __launch_bounds__(512) void ffn2_kernel(
    const unsigned short* __restrict__ hbuf,  // [TP][H] bf16
    const unsigned short* __restrict__ w2t,   // [E][D][H] bf16 (transposed)
    const float* __restrict__ b2,             // [E][D]
    const int* __restrict__ pair_token, const float* __restrict__ pair_w,
    const int4* __restrict__ tiles, const int* __restrict__ ntiles,
    float* __restrict__ out) {
  const int NB = D_DIM / BN;                  // 8
  const int nwg = MAX_TILES * NB;             // 576, %8==0
  int bid = blockIdx.x;
  int wg = (bid & 7) * (nwg >> 3) + (bid >> 3);
  int tileId = wg / NB, nb = wg - tileId * NB;
  if (tileId >= *ntiles) return;
  int4 tl = tiles[tileId];
  const int e = tl.x, row0 = tl.y, rows = tl.z;
  const int n0 = nb * BN;

  __shared__ unsigned short As[2][2][BM * BKS];  // [group][buf] 2x2x8KB
  __shared__ unsigned short Bs[2][2][BN * BKS];  // [group][buf] 2x2x8KB -> 64KB total
  __shared__ int stok[BM];
  __shared__ float spw[BM];

  const int tid = threadIdx.x;
  if (tid < BM) {
    int rr = row0 + tid; if (rr > TP - 1) rr = TP - 1;
    stok[tid] = pair_token[rr];
    spw[tid] = pair_w[rr];
  }

  const int g = tid >> 8;                     // K-group 0/1
  const int t4 = tid & 255;                   // index within group
  const int wid4 = t4 >> 6, lane = tid & 63;
  const int sr = t4 >> 2;                     // staging row 0..63 (and +64)
  const int sc = tid & 3;
  const int scz = SWZ(sr, sc) * 8;
  const int kbase = g * (H_DIM / 2);          // 0 or 2048 (shorts)

  int r0a = row0 + sr;       if (r0a > TP - 1) r0a = TP - 1;
  int r1a = row0 + sr + 64;  if (r1a > TP - 1) r1a = TP - 1;
  const unsigned short* a0 = hbuf + (size_t)r0a * H_DIM + kbase + scz;
  const unsigned short* a1 = hbuf + (size_t)r1a * H_DIM + kbase + scz;
  const unsigned short* bp0 = w2t + ((size_t)e * D_DIM + (n0 + sr)) * H_DIM + kbase + scz;
  const unsigned short* bp1 = w2t + ((size_t)e * D_DIM + (n0 + sr + 64)) * H_DIM + kbase + scz;

  const int wbase = wid4 * 512;               // wave-uniform LDS offset within group (shorts)
  const int wr = wid4 >> 1, wc = wid4 & 1;
  const int lrow = lane & 15, lkc = lane >> 4;

  f32x4 acc[4][4] = {};

  auto stage = [&](int buf, int k0) {         // exactly 4 VMEM ops per wave
    gload16(a0 + k0, &As[g][buf][wbase]);
    gload16(a1 + k0, &As[g][buf][wbase + 2048]);
    gload16(bp0 + k0, &Bs[g][buf][wbase]);
    gload16(bp1 + k0, &Bs[g][buf][wbase + 2048]);
  };
  auto compute_step = [&](int buf) {
    bf16x8 af[4], bfr[4];
#pragma unroll
    for (int m = 0; m < 4; ++m) {
      int r = wr * 64 + m * 16 + lrow;
      af[m] = *(const bf16x8*)(&As[g][buf][r * BKS + SWZ(r, lkc) * 8]);
    }
#pragma unroll
    for (int n = 0; n < 4; ++n) {
      int r = wc * 64 + n * 16 + lrow;
      bfr[n] = *(const bf16x8*)(&Bs[g][buf][r * BKS + SWZ(r, lkc) * 8]);
    }
#pragma unroll
    for (int m = 0; m < 4; ++m)
#pragma unroll
      for (int n = 0; n < 4; ++n)
        acc[m][n] = __builtin_amdgcn_mfma_f32_16x16x32_bf16(af[m], bfr[n], acc[m][n], 0, 0, 0);
  };

  const int NK = (H_DIM / 2) / BKS;           // 64 steps per group
  stage(0, 0);
  stage(1, BKS);
  int cur = 0;
  for (int k = 0; k < NK - 1; ++k) {
    asm volatile("s_waitcnt vmcnt(4)" ::: "memory");  // own group's cur loads done
    __builtin_amdgcn_s_barrier();
    __builtin_amdgcn_sched_barrier(0);
    compute_step(cur);
    __builtin_amdgcn_sched_barrier(0);
    __builtin_amdgcn_s_barrier();
    if (k < NK - 2) stage(cur, (k + 2) * BKS);
    cur ^= 1;
  }
  asm volatile("s_waitcnt vmcnt(0)" ::: "memory");
  __builtin_amdgcn_s_barrier();
  __builtin_amdgcn_sched_barrier(0);
  compute_step(cur);

  const int colbase = n0 + wc * 64;
#pragma unroll
  for (int n = 0; n < 4; ++n) {
    int colg = colbase + n * 16 + lrow;
    float bias = (g == 0) ? b2[(size_t)e * D_DIM + colg] : 0.f;
#pragma unroll
    for (int m = 0; m < 4; ++m) {
      int rbase = wr * 64 + m * 16 + (lane >> 4) * 4;
#pragma unroll
      for (int j = 0; j < 4; ++j) {
        int rloc = rbase + j;
        if (rloc < rows) {
          float v = acc[m][n][j] + bias;
          // 4 atomic adds per output element (2 experts x 2 K-groups)
          unsafeAtomicAdd(&out[(size_t)stok[rloc] * D_DIM + colg], spw[rloc] * v);
        }
      }
    }
  }
}

// ---------------- load-balancing loss: deterministic fixed-order reduction ----------------
__global__ __launch_bounds__(256) void loss_kernel(
    const float* __restrict__ gp_tok, const int* __restrict__ counts,
    float* __restrict__ out) {
  __shared__ float red[256];
  const int tid = threadIdx.x;
  float part[8] = {0, 0, 0, 0, 0, 0, 0, 0};
  for (int r = tid; r < T_TOK; r += 256) {
    const float* g = gp_tok + (size_t)r * 8;
#pragma unroll
    for (int e = 0; e < 8; ++e) part[e] += g[e];
  }
  float total[8];
#pragma unroll
  for (int e = 0; e < 8; ++e) {
    red[tid] = part[e];
    __syncthreads();
    for (int s = 128; s > 0; s >>= 1) {
      if (tid < s) red[tid] += red[tid + s];
      __syncthreads();
    }
    if (tid == 0) total[e] = red[0];
    __syncthreads();
  }
  if (tid == 0) {
    float ll = 0.f;
#pragma unroll
    for (int e = 0; e < 8; ++e)
      ll += ((float)counts[e] / (float)TP) * (total[e] / (float)T_TOK);
    out[(size_t)T_TOK * D_DIM] = ll * (float)E_EXP;
  }
}

extern "C" void kernel_launch(void* const* d_in, const int* in_sizes, int n_in,
                              void* d_out, int out_size, void* d_ws, size_t ws_size,
                              hipStream_t stream) {
  (void)in_sizes; (void)n_in; (void)ws_size;
  const float* x     = (const float*)d_in[0];
  const float* noise = (const float*)d_in[1];
  const float* Wg    = (const float*)d_in[2];
  const float* bg    = (const float*)d_in[3];
  const float* Wn    = (const float*)d_in[4];
  const float* bn    = (const float*)d_in[5];
  const float* W1    = (const float*)d_in[6];
  const float* b1    = (const float*)d_in[7];
  const float* W2    = (const float*)d_in[8];
  const float* b2    = (const float*)d_in[9];
  float* out = (float*)d_out;

  char* ws = (char*)d_ws;
  size_t o = 0;
  auto take = [&](size_t b) { size_t r = o; o += (b + 255) & ~(size_t)255; return r; };
  int*   counts     = (int*)(ws + take(16 * 4));        // counts[8] + cursor[8], zeroed
  int*   cursor     = counts + 8;
  int*   offsets    = (int*)(ws + take(9 * 4));
  int*   ntiles     = (int*)(ws + take(4));
  int4*  tiles      = (int4*)(ws + take(MAX_TILES * 16));
  int*   tok_e      = (int*)(ws + take((size_t)TP * 4));
  float* tok_w      = (float*)(ws + take((size_t)TP * 4));
  float* gp_tok     = (float*)(ws + take((size_t)T_TOK * 8 * 4));
  int*   pair_token = (int*)(ws + take((size_t)TP * 4));
  float* pair_w     = (float*)(ws + take((size_t)TP * 4));
  unsigned short* xb  = (unsigned short*)(ws + take((size_t)T_TOK * D_DIM * 2));
  unsigned short* w1t = (unsigned short*)(ws + take((size_t)E_EXP * H_DIM * D_DIM * 2));
  unsigned short* w2t = (unsigned short*)(ws + take((size_t)E_EXP * H_DIM * D_DIM * 2));
  unsigned short* hbuf = (unsigned short*)(ws + take((size_t)TP * H_DIM * 2));
  // total ws usage ~201 MB

  hipMemsetAsync(d_out, 0, (size_t)out_size * sizeof(float), stream);
  hipMemsetAsync(counts, 0, 16 * 4, stream);

  transpose_bf16_kernel<<<dim3(H_DIM / 64, D_DIM / 64, E_EXP), 256, 0, stream>>>(
      W1, w1t, D_DIM, H_DIM);
  transpose_bf16_kernel<<<dim3(D_DIM / 64, H_DIM / 64, E_EXP), 256, 0, stream>>>(
      W2, w2t, H_DIM, D_DIM);
  gating_kernel<<<T_TOK / 4, 256, 0, stream>>>(x, noise, Wg, bg, Wn, bn,
                                               tok_e, tok_w, gp_tok, counts, xb);
  scan_kernel<<<1, 64, 0, stream>>>(counts, offsets, cursor, tiles, ntiles);
  scatter_kernel<<<T_TOK / 256, 256, 0, stream>>>(tok_e, tok_w, offsets, cursor,
                                                  pair_token, pair_w);
  ffn1_kernel<<<dim3(MAX_TILES * (H_DIM / BN)), 256, 0, stream>>>(
      xb, w1t, b1, pair_token, tiles, ntiles, hbuf);
  ffn2_kernel<<<dim3(MAX_TILES * (D_DIM / BN)), 512, 0, stream>>>(
      hbuf, w2t, b2, pair_token, pair_w, tiles, ntiles, out);
  loss_kernel<<<1, 256, 0, stream>>>(gp_tok, counts, out);
}

// Round 12
// 534.990 us; speedup vs baseline: 1.0546x; 1.0546x over previous
//
#include <hip/hip_runtime.h>
#include <hip/hip_bf16.h>

// Problem constants
#define T_TOK 4096          // B*S tokens
#define D_DIM 1024
#define H_DIM 4096
#define E_EXP 8
#define K_TOP 2
#define TP (T_TOK * K_TOP)  // 8192 (token, expert) pairs
#define BM 128
#define BN 128
#define BKS 32              // K-step (shorts) -- r2/r5-verified
#define MAX_TILES 72

typedef __attribute__((ext_vector_type(8))) short bf16x8;
typedef __attribute__((ext_vector_type(4))) float f32x4;
typedef __attribute__((ext_vector_type(8))) unsigned short u16x8;
typedef __attribute__((ext_vector_type(4))) unsigned short u16x4;

// LDS chunk swizzle: permute the four 16B chunks within a row's 64B slab.
// Applied identically on the global source column (same 64B segment ->
// coalescing unchanged) and on the LDS fragment read.
// Verified r2/r5/r6/r8/r10: SQ_LDS_BANK_CONFLICT == 0.
#define SWZ(row, chunk) ((chunk) ^ (((row) >> 1) & 3))

static __device__ __forceinline__ void gload16(const unsigned short* g, unsigned short* l) {
  // async global->LDS, 16B per lane; LDS dest = wave-uniform base + lane*16
  __builtin_amdgcn_global_load_lds((const __attribute__((address_space(1))) void*)g,
                                   (__attribute__((address_space(3))) void*)l, 16, 0, 0);
}

static __device__ __forceinline__ unsigned short f2bf(float f) {
  // round-to-nearest-even fp32 -> bf16
  unsigned int bits = __float_as_uint(f);
  unsigned int lsb = (bits >> 16) & 1u;
  bits += 0x7fffu + lsb;
  return (unsigned short)(bits >> 16);
}

static __device__ __forceinline__ float gelu_fast(float u) {
  // tanh-form gelu: u * sigmoid(1.5957691 * (u + 0.044715 u^3)); |err| <~ 3e-4
  float z = u * (0.79788456080286536f + 0.0356774081f * u * u);
  float t = __expf(-2.f * z);
  return u / (1.f + t);
}

// ---------------- transpose + convert: src [E][R][C] fp32 -> dst [E][C][R] bf16 ----------------
// r8-verified: 64x64 tiles; float4 reads; fp32 LDS [64][65]; u16x8 writes.
__global__ __launch_bounds__(256) void transpose_bf16_kernel(
    const float* __restrict__ src, unsigned short* __restrict__ dst, int R, int C) {
  __shared__ float tile[64][65];
  const int e = blockIdx.z;
  const int c0 = blockIdx.x * 64, r0 = blockIdx.y * 64;
  const int tid = threadIdx.x;
  const float* s = src + (size_t)e * R * C;
  unsigned short* d = dst + (size_t)e * R * C;

  // read: 64 rows x 16 float4; lane (row=tid>>4, c4=tid&15), 4 passes
  const int rr = tid >> 4, c4 = tid & 15;
#pragma unroll
  for (int p = 0; p < 4; ++p) {
    int r = rr + p * 16;
    float4 v = *(const float4*)(&s[(size_t)(r0 + r) * C + c0 + c4 * 4]);
    tile[r][c4 * 4 + 0] = v.x;
    tile[r][c4 * 4 + 1] = v.y;
    tile[r][c4 * 4 + 2] = v.z;
    tile[r][c4 * 4 + 3] = v.w;
  }
  __syncthreads();
  // write: out row c (64 bf16 = 128B); lane (c=tid>>3, r8=tid&7), 2 passes
  const int cc = tid >> 3, r8 = tid & 7;
#pragma unroll
  for (int p = 0; p < 2; ++p) {
    int c = cc + p * 32;
    u16x8 o;
#pragma unroll
    for (int q = 0; q < 8; ++q) o[q] = f2bf(tile[r8 * 8 + q][c]);
    *(u16x8*)(&d[(size_t)(c0 + c) * R + r0 + r8 * 8]) = o;
  }
}

// ---------------- gating: fp32 exact, one wave per token ----------------
// r9-verified: also emits xb (bf16 copy of x) -- fuses the former convert_x kernel.
__global__ __launch_bounds__(256) void gating_kernel(
    const float* __restrict__ x, const float* __restrict__ noise,
    const float* __restrict__ Wg, const float* __restrict__ bg,
    const float* __restrict__ Wn, const float* __restrict__ bn,
    int* __restrict__ tok_e, float* __restrict__ tok_w,
    float* __restrict__ gp_tok, int* __restrict__ counts,
    unsigned short* __restrict__ xb) {
  const int tid = threadIdx.x, lane = tid & 63, wid = tid >> 6;
  const int t = blockIdx.x * 4 + wid;
  const float* xrow = x + (size_t)t * D_DIM;
  float ag[8] = {0, 0, 0, 0, 0, 0, 0, 0};
  float an[8] = {0, 0, 0, 0, 0, 0, 0, 0};
#pragma unroll 4
  for (int i = 0; i < 16; ++i) {
    int dd = i * 64 + lane;
    float xv = xrow[dd];
    xb[(size_t)t * D_DIM + dd] = f2bf(xv);          // fused x -> bf16 (coalesced 128B/wave)
    const float4* g4 = (const float4*)(Wg + (size_t)dd * 8);
    const float4* n4 = (const float4*)(Wn + (size_t)dd * 8);
    float4 ga = g4[0], gb = g4[1], na = n4[0], nb = n4[1];
    ag[0] += xv * ga.x; ag[1] += xv * ga.y; ag[2] += xv * ga.z; ag[3] += xv * ga.w;
    ag[4] += xv * gb.x; ag[5] += xv * gb.y; ag[6] += xv * gb.z; ag[7] += xv * gb.w;
    an[0] += xv * na.x; an[1] += xv * na.y; an[2] += xv * na.z; an[3] += xv * na.w;
    an[4] += xv * nb.x; an[5] += xv * nb.y; an[6] += xv * nb.z; an[7] += xv * nb.w;
  }
#pragma unroll
  for (int e = 0; e < 8; ++e) {
    for (int off = 32; off > 0; off >>= 1) {
      ag[e] += __shfl_down(ag[e], off);
      an[e] += __shfl_down(an[e], off);
    }
  }
  if (lane == 0) {
    float logit[8], noisy[8];
#pragma unroll
    for (int e = 0; e < 8; ++e) {
      logit[e] = ag[e] + bg[e];
      float pre = an[e] + bn[e];
      float sp = fmaxf(pre, 0.f) + log1pf(expf(-fabsf(pre)));   // softplus, stable
      noisy[e] = logit[e] + noise[(size_t)t * 8 + e] * sp;
    }
    // clean-gate softmax for load loss
    float mx = logit[0];
#pragma unroll
    for (int e = 1; e < 8; ++e) mx = fmaxf(mx, logit[e]);
    float s = 0.f, p[8];
#pragma unroll
    for (int e = 0; e < 8; ++e) { p[e] = expf(logit[e] - mx); s += p[e]; }
    float inv = 1.f / s;
#pragma unroll
    for (int e = 0; e < 8; ++e) gp_tok[(size_t)t * 8 + e] = p[e] * inv;
    // top-2 (strict > keeps lowest index on ties, matching lax.top_k)
    int i0 = 0; float v0 = noisy[0];
#pragma unroll
    for (int e = 1; e < 8; ++e) if (noisy[e] > v0) { v0 = noisy[e]; i0 = e; }
    int i1 = -1; float v1 = 0.f;
#pragma unroll
    for (int e = 0; e < 8; ++e) {
      if (e == i0) continue;
      if (i1 < 0 || noisy[e] > v1) { v1 = noisy[e]; i1 = e; }
    }
    float e1 = expf(v1 - v0);        // v0 >= v1
    float w0 = 1.f / (1.f + e1);
    float w1 = e1 * w0;
    tok_e[t * 2 + 0] = i0; tok_e[t * 2 + 1] = i1;
    tok_w[t * 2 + 0] = w0; tok_w[t * 2 + 1] = w1;
    atomicAdd(&counts[i0], 1);
    atomicAdd(&counts[i1], 1);
  }
}

// ---------------- scan: offsets + tile table (1 thread, trivial) ----------------
__global__ void scan_kernel(const int* __restrict__ counts, int* __restrict__ offsets,
                            int* __restrict__ cursor, int4* __restrict__ tiles,
                            int* __restrict__ ntiles) {
  if (threadIdx.x == 0 && blockIdx.x == 0) {
    int off = 0, nt = 0;
    for (int e = 0; e < E_EXP; ++e) {
      offsets[e] = off;
      int c = counts[e];
      for (int r = 0; r < c; r += BM) {
        tiles[nt] = make_int4(e, off + r, min(BM, c - r), 0);
        ++nt;
      }
      off += c;
      cursor[e] = 0;
    }
    offsets[E_EXP] = off;
    *ntiles = nt;
  }
}

// ---------------- scatter tokens into compact per-expert pair lists ----------------
__global__ __launch_bounds__(256) void scatter_kernel(
    const int* __restrict__ tok_e, const float* __restrict__ tok_w,
    const int* __restrict__ offsets, int* __restrict__ cursor,
    int* __restrict__ pair_token, float* __restrict__ pair_w) {
  int t = blockIdx.x * 256 + threadIdx.x;
  if (t >= T_TOK) return;
#pragma unroll
  for (int k = 0; k < 2; ++k) {
    int e = tok_e[t * 2 + k];
    int pos = atomicAdd(&cursor[e], 1);
    int p = offsets[e] + pos;
    pair_token[p] = t;
    pair_w[p] = tok_w[t * 2 + k];
  }
}

// ---------------- FFN1: h = gelu(X_e @ W1_e + b1_e), grouped GEMM, bf16 MFMA ----------------
// r6/r8/r10-verified: counted vmcnt(4) depth-2 pipeline + coalesced LDS epilogue.
__global__ __launch_bounds__(256) void ffn1_kernel(
    const unsigned short* __restrict__ xb,    // [T][D] bf16
    const unsigned short* __restrict__ w1t,   // [E][H][D] bf16 (transposed)
    const float* __restrict__ b1,             // [E][H]
    const int* __restrict__ pair_token,       // [TP]
    const int4* __restrict__ tiles, const int* __restrict__ ntiles,
    unsigned short* __restrict__ hbuf) {      // [TP][H] bf16
  const int NB = H_DIM / BN;                  // 32
  const int nwg = MAX_TILES * NB;             // 2304, %8==0
  int bid = blockIdx.x;
  int wg = (bid & 7) * (nwg >> 3) + (bid >> 3);   // bijective XCD chunking
  int tileId = wg / NB, nb = wg - tileId * NB;    // tile-major within an XCD
  if (tileId >= *ntiles) return;
  int4 tl = tiles[tileId];
  const int e = tl.x, row0 = tl.y, rows = tl.z;
  const int n0 = nb * BN;

  __shared__ unsigned short sh[16384];        // 32KB: As(2x8KB)+Bs(2x8KB); reused as [128][128] epilogue tile
#define AS1(buf) (sh + (buf) * 4096)
#define BS1(buf) (sh + 8192 + (buf) * 4096)

  const int tid = threadIdx.x;
  const int wid = tid >> 6, lane = tid & 63;
  const int sr = tid >> 2;                    // local row 0..63 (and +64)
  const int sc = tid & 3;                     // 16B chunk 0..3
  const int scz = SWZ(sr, sc) * 8;            // swizzled source column (shorts)

  int r0a = row0 + sr;       if (r0a > TP - 1) r0a = TP - 1;
  int r1a = row0 + sr + 64;  if (r1a > TP - 1) r1a = TP - 1;
  const unsigned short* a0 = xb + (size_t)pair_token[r0a] * D_DIM + scz;
  const unsigned short* a1 = xb + (size_t)pair_token[r1a] * D_DIM + scz;
  const unsigned short* bp0 = w1t + ((size_t)e * H_DIM + (n0 + sr)) * D_DIM + scz;
  const unsigned short* bp1 = w1t + ((size_t)e * H_DIM + (n0 + sr + 64)) * D_DIM + scz;

  const int wbase = wid * 512;                // wave-uniform LDS offset (shorts)
  const int wr = wid >> 1, wc = wid & 1;
  const int lrow = lane & 15, lkc = lane >> 4;  // fragment chunk 0..3

  f32x4 acc[4][4] = {};

  auto stage = [&](int buf, int k0) {         // exactly 4 VMEM ops per wave
    gload16(a0 + k0, AS1(buf) + wbase);
    gload16(a1 + k0, AS1(buf) + wbase + 2048);
    gload16(bp0 + k0, BS1(buf) + wbase);
    gload16(bp1 + k0, BS1(buf) + wbase + 2048);
  };
  auto compute_step = [&](int buf) {
    bf16x8 af[4], bfr[4];
#pragma unroll
    for (int m = 0; m < 4; ++m) {
      int r = wr * 64 + m * 16 + lrow;
      af[m] = *(const bf16x8*)(AS1(buf) + r * BKS + SWZ(r, lkc) * 8);
    }
#pragma unroll
    for (int n = 0; n < 4; ++n) {
      int r = wc * 64 + n * 16 + lrow;
      bfr[n] = *(const bf16x8*)(BS1(buf) + r * BKS + SWZ(r, lkc) * 8);
    }
#pragma unroll
    for (int m = 0; m < 4; ++m)
#pragma unroll
      for (int n = 0; n < 4; ++n)
        acc[m][n] = __builtin_amdgcn_mfma_f32_16x16x32_bf16(af[m], bfr[n], acc[m][n], 0, 0, 0);
  };

  const int NK = D_DIM / BKS;                 // 32
  stage(0, 0);
  stage(1, BKS);
  int cur = 0;
  for (int k = 0; k < NK - 1; ++k) {
    asm volatile("s_waitcnt vmcnt(4)" ::: "memory");  // cur's 4 loads done; next 4 in flight
    __builtin_amdgcn_s_barrier();
    __builtin_amdgcn_sched_barrier(0);        // pin ds_reads after barrier
    compute_step(cur);
    __builtin_amdgcn_sched_barrier(0);
    __builtin_amdgcn_s_barrier();             // all reads of buf[cur] retired
    if (k < NK - 2) stage(cur, (k + 2) * BKS);  // refill (uniform branch)
    cur ^= 1;
  }
  asm volatile("s_waitcnt vmcnt(0)" ::: "memory");
  __builtin_amdgcn_s_barrier();
  __builtin_amdgcn_sched_barrier(0);
  compute_step(cur);

  // ---- epilogue: gelu -> LDS [128][128] (chunk-XOR swizzled) -> coalesced stores ----
  __syncthreads();                            // everyone done reading staging LDS
#pragma unroll
  for (int n = 0; n < 4; ++n) {
    int clocal = wc * 64 + n * 16 + lrow;
    float bias = b1[(size_t)e * H_DIM + n0 + clocal];
    int chunk = clocal >> 3, within = clocal & 7;
#pragma unroll
    for (int m = 0; m < 4; ++m) {
#pragma unroll
      for (int j = 0; j < 4; ++j) {
        int rloc = wr * 64 + m * 16 + (lane >> 4) * 4 + j;
        float v = acc[m][n][j] + bias;
        sh[rloc * 128 + ((chunk ^ ((rloc >> 1) & 7)) * 8) + within] = f2bf(gelu_fast(v));
      }
    }
  }
  __syncthreads();
#pragma unroll
  for (int it = 0; it < 8; ++it) {
    int u = tid + 256 * it;                   // 0..2047: row = u>>4, 16B-chunk = u&15
    int r = u >> 4, cg = u & 15;
    if (r < rows) {
      u16x8 v = *(const u16x8*)(&sh[r * 128 + ((cg ^ ((r >> 1) & 7)) * 8)]);
      *(u16x8*)(&hbuf[(size_t)(row0 + r) * H_DIM + n0 + cg * 8]) = v;  // 256B runs/row
    }
  }
#undef AS1
#undef BS1
}

// ---------------- FFN2: out[token] += w * (h_e @ W2_e + b2_e) ----------------
// r12: quad-buffer single-barrier pipeline. Same tile (128x128), same per-step
// staging (16KB) and FETCH as r8; but stage at step k targets step k+3
// (load window 2 full steps vs r8's 1) and ONE s_barrier per step (128 vs 256).
// Safety: per-wave vmcnt drain before barrier => all waves' current-buffer
// loads complete after barrier; stage at step k writes the buffer consumed at
// step k-1 whose readers all passed the step-k barrier => no WAR race.
__global__ __launch_bounds__(256) void ffn2_kernel(
    const unsigned short* __restrict__ hbuf,  // [TP][H] bf16
    const unsigned short* __restrict__ w2t,   // [E][D][H] bf16 (transposed)
    const float* __restrict__ b2,             // [E][D]
    const int* __restrict__ pair_token, const float* __restrict__ pair_w,
    const int4* __restrict__ tiles, const int* __restrict__ ntiles,
    float* __restrict__ out) {
  const int NB = D_DIM / BN;                  // 8
  const int nwg = MAX_TILES * NB;             // 576, %8==0
  int bid = blockIdx.x;
  int wg = (bid & 7) * (nwg >> 3) + (bid >> 3);
  int tileId = wg / NB, nb = wg - tileId * NB;
  if (tileId >= *ntiles) return;
  int4 tl = tiles[tileId];
  const int e = tl.x, row0 = tl.y, rows = tl.z;
  const int n0 = nb * BN;

  __shared__ unsigned short As[4][BM * BKS];  // 4 x 8KB
  __shared__ unsigned short Bs[4][BN * BKS];  // 4 x 8KB -> 64KB staging
  __shared__ int stok[BM];
  __shared__ float spw[BM];

  const int tid = threadIdx.x;
  if (tid < BM) {
    int rr = row0 + tid; if (rr > TP - 1) rr = TP - 1;
    stok[tid] = pair_token[rr];
    spw[tid] = pair_w[rr];
  }

  const int wid = tid >> 6, lane = tid & 63;
  const int sr = tid >> 2;
  const int sc = tid & 3;
  const int scz = SWZ(sr, sc) * 8;

  int r0a = row0 + sr;       if (r0a > TP - 1) r0a = TP - 1;
  int r1a = row0 + sr + 64;  if (r1a > TP - 1) r1a = TP - 1;
  const unsigned short* a0 = hbuf + (size_t)r0a * H_DIM + scz;
  const unsigned short* a1 = hbuf + (size_t)r1a * H_DIM + scz;
  const unsigned short* bp0 = w2t + ((size_t)e * D_DIM + (n0 + sr)) * H_DIM + scz;
  const unsigned short* bp1 = w2t + ((size_t)e * D_DIM + (n0 + sr + 64)) * H_DIM + scz;

  const int wbase = wid * 512;
  const int wr = wid >> 1, wc = wid & 1;
  const int lrow = lane & 15, lkc = lane >> 4;

  f32x4 acc[4][4] = {};

  auto stage = [&](int buf, int k0) {         // exactly 4 VMEM ops per wave
    gload16(a0 + k0, &As[buf][wbase]);
    gload16(a1 + k0, &As[buf][wbase + 2048]);
    gload16(bp0 + k0, &Bs[buf][wbase]);
    gload16(bp1 + k0, &Bs[buf][wbase + 2048]);
  };
  auto compute_step = [&](int buf) {
    bf16x8 af[4], bfr[4];
#pragma unroll
    for (int m = 0; m < 4; ++m) {
      int r = wr * 64 + m * 16 + lrow;
      af[m] = *(const bf16x8*)(&As[buf][r * BKS + SWZ(r, lkc) * 8]);
    }
#pragma unroll
    for (int n = 0; n < 4; ++n) {
      int r = wc * 64 + n * 16 + lrow;
      bfr[n] = *(const bf16x8*)(&Bs[buf][r * BKS + SWZ(r, lkc) * 8]);
    }
#pragma unroll
    for (int m = 0; m < 4; ++m)
#pragma unroll
      for (int n = 0; n < 4; ++n)
        acc[m][n] = __builtin_amdgcn_mfma_f32_16x16x32_bf16(af[m], bfr[n], acc[m][n], 0, 0, 0);
  };

  const int NK = H_DIM / BKS;                 // 128
  // prologue: fill all 4 buffers (16 loads in flight per wave)
  stage(0, 0);
  stage(1, BKS);
  stage(2, 2 * BKS);
  stage(3, 3 * BKS);
  // step 0: 16 outstanding -> drain oldest 4
  asm volatile("s_waitcnt vmcnt(12)" ::: "memory");
  __builtin_amdgcn_s_barrier();
  __builtin_amdgcn_sched_barrier(0);
  compute_step(0);
  __builtin_amdgcn_sched_barrier(0);
  // steps 1..NK-4: steady state, 12 outstanding at top; stage step k+3 into
  // the buffer consumed at step k-1 (freed by this step's barrier)
  for (int k = 1; k <= NK - 4; ++k) {
    asm volatile("s_waitcnt vmcnt(8)" ::: "memory");
    __builtin_amdgcn_s_barrier();
    __builtin_amdgcn_sched_barrier(0);
    compute_step(k & 3);
    __builtin_amdgcn_sched_barrier(0);
    stage((k + 3) & 3, (k + 3) * BKS);
  }
  // tail: steps NK-3, NK-2, NK-1 (no more stages)
  asm volatile("s_waitcnt vmcnt(8)" ::: "memory");
  __builtin_amdgcn_s_barrier();
  __builtin_amdgcn_sched_barrier(0);
  compute_step((NK - 3) & 3);
  __builtin_amdgcn_sched_barrier(0);
  asm volatile("s_waitcnt vmcnt(4)" ::: "memory");
  __builtin_amdgcn_s_barrier();
  __builtin_amdgcn_sched_barrier(0);
  compute_step((NK - 2) & 3);
  __builtin_amdgcn_sched_barrier(0);
  asm volatile("s_waitcnt vmcnt(0)" ::: "memory");
  __builtin_amdgcn_s_barrier();
  __builtin_amdgcn_sched_barrier(0);
  compute_step((NK - 1) & 3);

  const int colbase = n0 + wc * 64;
#pragma unroll
  for (int n = 0; n < 4; ++n) {
    int colg = colbase + n * 16 + lrow;
    float bias = b2[(size_t)e * D_DIM + colg];
#pragma unroll
    for (int m = 0; m < 4; ++m) {
      int rbase = wr * 64 + m * 16 + (lane >> 4) * 4;
#pragma unroll
      for (int j = 0; j < 4; ++j) {
        int rloc = rbase + j;
        if (rloc < rows) {
          float v = acc[m][n][j] + bias;
          // exactly 2 atomic adds per output element (one per selected expert);
          // fp32 add is commutative -> deterministic for 2 contributions
          unsafeAtomicAdd(&out[(size_t)stok[rloc] * D_DIM + colg], spw[rloc] * v);
        }
      }
    }
  }
}

// ---------------- load-balancing loss: deterministic fixed-order reduction ----------------
__global__ __launch_bounds__(256) void loss_kernel(
    const float* __restrict__ gp_tok, const int* __restrict__ counts,
    float* __restrict__ out) {
  __shared__ float red[256];
  const int tid = threadIdx.x;
  float part[8] = {0, 0, 0, 0, 0, 0, 0, 0};
  for (int r = tid; r < T_TOK; r += 256) {
    const float* g = gp_tok + (size_t)r * 8;
#pragma unroll
    for (int e = 0; e < 8; ++e) part[e] += g[e];
  }
  float total[8];
#pragma unroll
  for (int e = 0; e < 8; ++e) {
    red[tid] = part[e];
    __syncthreads();
    for (int s = 128; s > 0; s >>= 1) {
      if (tid < s) red[tid] += red[tid + s];
      __syncthreads();
    }
    if (tid == 0) total[e] = red[0];
    __syncthreads();
  }
  if (tid == 0) {
    float ll = 0.f;
#pragma unroll
    for (int e = 0; e < 8; ++e)
      ll += ((float)counts[e] / (float)TP) * (total[e] / (float)T_TOK);
    out[(size_t)T_TOK * D_DIM] = ll * (float)E_EXP;
  }
}

extern "C" void kernel_launch(void* const* d_in, const int* in_sizes, int n_in,
                              void* d_out, int out_size, void* d_ws, size_t ws_size,
                              hipStream_t stream) {
  (void)in_sizes; (void)n_in; (void)ws_size;
  const float* x     = (const float*)d_in[0];
  const float* noise = (const float*)d_in[1];
  const float* Wg    = (const float*)d_in[2];
  const float* bg    = (const float*)d_in[3];
  const float* Wn    = (const float*)d_in[4];
  const float* bn    = (const float*)d_in[5];
  const float* W1    = (const float*)d_in[6];
  const float* b1    = (const float*)d_in[7];
  const float* W2    = (const float*)d_in[8];
  const float* b2    = (const float*)d_in[9];
  float* out = (float*)d_out;

  char* ws = (char*)d_ws;
  size_t o = 0;
  auto take = [&](size_t b) { size_t r = o; o += (b + 255) & ~(size_t)255; return r; };
  int*   counts     = (int*)(ws + take(16 * 4));        // counts[8] + cursor[8], zeroed
  int*   cursor     = counts + 8;
  int*   offsets    = (int*)(ws + take(9 * 4));
  int*   ntiles     = (int*)(ws + take(4));
  int4*  tiles      = (int4*)(ws + take(MAX_TILES * 16));
  int*   tok_e      = (int*)(ws + take((size_t)TP * 4));
  float* tok_w      = (float*)(ws + take((size_t)TP * 4));
  float* gp_tok     = (float*)(ws + take((size_t)T_TOK * 8 * 4));
  int*   pair_token = (int*)(ws + take((size_t)TP * 4));
  float* pair_w     = (float*)(ws + take((size_t)TP * 4));
  unsigned short* xb  = (unsigned short*)(ws + take((size_t)T_TOK * D_DIM * 2));
  unsigned short* w1t = (unsigned short*)(ws + take((size_t)E_EXP * H_DIM * D_DIM * 2));
  unsigned short* w2t = (unsigned short*)(ws + take((size_t)E_EXP * H_DIM * D_DIM * 2));
  unsigned short* hbuf = (unsigned short*)(ws + take((size_t)TP * H_DIM * 2));
  // total ws usage ~201 MB

  hipMemsetAsync(d_out, 0, (size_t)out_size * sizeof(float), stream);
  hipMemsetAsync(counts, 0, 16 * 4, stream);

  transpose_bf16_kernel<<<dim3(H_DIM / 64, D_DIM / 64, E_EXP), 256, 0, stream>>>(
      W1, w1t, D_DIM, H_DIM);
  transpose_bf16_kernel<<<dim3(D_DIM / 64, H_DIM / 64, E_EXP), 256, 0, stream>>>(
      W2, w2t, H_DIM, D_DIM);
  gating_kernel<<<T_TOK / 4, 256, 0, stream>>>(x, noise, Wg, bg, Wn, bn,
                                               tok_e, tok_w, gp_tok, counts, xb);
  scan_kernel<<<1, 64, 0, stream>>>(counts, offsets, cursor, tiles, ntiles);
  scatter_kernel<<<T_TOK / 256, 256, 0, stream>>>(tok_e, tok_w, offsets, cursor,
                                                  pair_token, pair_w);
  ffn1_kernel<<<dim3(MAX_TILES * (H_DIM / BN)), 256, 0, stream>>>(
      xb, w1t, b1, pair_token, tiles, ntiles, hbuf);
  ffn2_kernel<<<dim3(MAX_TILES * (D_DIM / BN)), 256, 0, stream>>>(
      hbuf, w2t, b2, pair_token, pair_w, tiles, ntiles, out);
  loss_kernel<<<1, 256, 0, stream>>>(gp_tok, counts, out);
}

// Round 13
// 498.903 us; speedup vs baseline: 1.1309x; 1.0723x over previous
//
#include <hip/hip_runtime.h>
#include <hip/hip_bf16.h>

// Problem constants
#define T_TOK 4096          // B*S tokens
#define D_DIM 1024
#define H_DIM 4096
#define E_EXP 8
#define K_TOP 2
#define TP (T_TOK * K_TOP)  // 8192 (token, expert) pairs
#define BM 128              // ffn2 M-tile
#define BN 128
#define BM1 256             // ffn1 M-tile (r13)
#define BKS 32              // K-step (shorts) -- r2/r5-verified
#define MAX_TILES 72        // 128-row tiles
#define MAX_T256 48         // 256-row tiles (<=39 worst case)

typedef __attribute__((ext_vector_type(8))) short bf16x8;
typedef __attribute__((ext_vector_type(4))) float f32x4;
typedef __attribute__((ext_vector_type(8))) unsigned short u16x8;
typedef __attribute__((ext_vector_type(4))) unsigned short u16x4;

// LDS chunk swizzle: permute the four 16B chunks within a row's 64B slab.
// Applied identically on the global source column (same 64B segment ->
// coalescing unchanged) and on the LDS fragment read.
// Verified r2/r5/r6/r8/r10: SQ_LDS_BANK_CONFLICT == 0.
#define SWZ(row, chunk) ((chunk) ^ (((row) >> 1) & 3))

static __device__ __forceinline__ void gload16(const unsigned short* g, unsigned short* l) {
  // async global->LDS, 16B per lane; LDS dest = wave-uniform base + lane*16
  __builtin_amdgcn_global_load_lds((const __attribute__((address_space(1))) void*)g,
                                   (__attribute__((address_space(3))) void*)l, 16, 0, 0);
}

static __device__ __forceinline__ unsigned short f2bf(float f) {
  // round-to-nearest-even fp32 -> bf16
  unsigned int bits = __float_as_uint(f);
  unsigned int lsb = (bits >> 16) & 1u;
  bits += 0x7fffu + lsb;
  return (unsigned short)(bits >> 16);
}

static __device__ __forceinline__ float gelu_fast(float u) {
  // tanh-form gelu: u * sigmoid(1.5957691 * (u + 0.044715 u^3)); |err| <~ 3e-4
  float z = u * (0.79788456080286536f + 0.0356774081f * u * u);
  float t = __expf(-2.f * z);
  return u / (1.f + t);
}

// ---------------- transpose + convert: src [E][R][C] fp32 -> dst [E][C][R] bf16 ----------------
// r8-verified: 64x64 tiles; float4 reads; fp32 LDS [64][65]; u16x8 writes.
__global__ __launch_bounds__(256) void transpose_bf16_kernel(
    const float* __restrict__ src, unsigned short* __restrict__ dst, int R, int C) {
  __shared__ float tile[64][65];
  const int e = blockIdx.z;
  const int c0 = blockIdx.x * 64, r0 = blockIdx.y * 64;
  const int tid = threadIdx.x;
  const float* s = src + (size_t)e * R * C;
  unsigned short* d = dst + (size_t)e * R * C;

  const int rr = tid >> 4, c4 = tid & 15;
#pragma unroll
  for (int p = 0; p < 4; ++p) {
    int r = rr + p * 16;
    float4 v = *(const float4*)(&s[(size_t)(r0 + r) * C + c0 + c4 * 4]);
    tile[r][c4 * 4 + 0] = v.x;
    tile[r][c4 * 4 + 1] = v.y;
    tile[r][c4 * 4 + 2] = v.z;
    tile[r][c4 * 4 + 3] = v.w;
  }
  __syncthreads();
  const int cc = tid >> 3, r8 = tid & 7;
#pragma unroll
  for (int p = 0; p < 2; ++p) {
    int c = cc + p * 32;
    u16x8 o;
#pragma unroll
    for (int q = 0; q < 8; ++q) o[q] = f2bf(tile[r8 * 8 + q][c]);
    *(u16x8*)(&d[(size_t)(c0 + c) * R + r0 + r8 * 8]) = o;
  }
}

// ---------------- gating: fp32 exact, one wave per token ----------------
// r9-verified: also emits xb (bf16 copy of x) -- fuses the former convert_x kernel.
__global__ __launch_bounds__(256) void gating_kernel(
    const float* __restrict__ x, const float* __restrict__ noise,
    const float* __restrict__ Wg, const float* __restrict__ bg,
    const float* __restrict__ Wn, const float* __restrict__ bn,
    int* __restrict__ tok_e, float* __restrict__ tok_w,
    float* __restrict__ gp_tok, int* __restrict__ counts,
    unsigned short* __restrict__ xb) {
  const int tid = threadIdx.x, lane = tid & 63, wid = tid >> 6;
  const int t = blockIdx.x * 4 + wid;
  const float* xrow = x + (size_t)t * D_DIM;
  float ag[8] = {0, 0, 0, 0, 0, 0, 0, 0};
  float an[8] = {0, 0, 0, 0, 0, 0, 0, 0};
#pragma unroll 4
  for (int i = 0; i < 16; ++i) {
    int dd = i * 64 + lane;
    float xv = xrow[dd];
    xb[(size_t)t * D_DIM + dd] = f2bf(xv);          // fused x -> bf16 (coalesced 128B/wave)
    const float4* g4 = (const float4*)(Wg + (size_t)dd * 8);
    const float4* n4 = (const float4*)(Wn + (size_t)dd * 8);
    float4 ga = g4[0], gb = g4[1], na = n4[0], nb = n4[1];
    ag[0] += xv * ga.x; ag[1] += xv * ga.y; ag[2] += xv * ga.z; ag[3] += xv * ga.w;
    ag[4] += xv * gb.x; ag[5] += xv * gb.y; ag[6] += xv * gb.z; ag[7] += xv * gb.w;
    an[0] += xv * na.x; an[1] += xv * na.y; an[2] += xv * na.z; an[3] += xv * na.w;
    an[4] += xv * nb.x; an[5] += xv * nb.y; an[6] += xv * nb.z; an[7] += xv * nb.w;
  }
#pragma unroll
  for (int e = 0; e < 8; ++e) {
    for (int off = 32; off > 0; off >>= 1) {
      ag[e] += __shfl_down(ag[e], off);
      an[e] += __shfl_down(an[e], off);
    }
  }
  if (lane == 0) {
    float logit[8], noisy[8];
#pragma unroll
    for (int e = 0; e < 8; ++e) {
      logit[e] = ag[e] + bg[e];
      float pre = an[e] + bn[e];
      float sp = fmaxf(pre, 0.f) + log1pf(expf(-fabsf(pre)));   // softplus, stable
      noisy[e] = logit[e] + noise[(size_t)t * 8 + e] * sp;
    }
    // clean-gate softmax for load loss
    float mx = logit[0];
#pragma unroll
    for (int e = 1; e < 8; ++e) mx = fmaxf(mx, logit[e]);
    float s = 0.f, p[8];
#pragma unroll
    for (int e = 0; e < 8; ++e) { p[e] = expf(logit[e] - mx); s += p[e]; }
    float inv = 1.f / s;
#pragma unroll
    for (int e = 0; e < 8; ++e) gp_tok[(size_t)t * 8 + e] = p[e] * inv;
    // top-2 (strict > keeps lowest index on ties, matching lax.top_k)
    int i0 = 0; float v0 = noisy[0];
#pragma unroll
    for (int e = 1; e < 8; ++e) if (noisy[e] > v0) { v0 = noisy[e]; i0 = e; }
    int i1 = -1; float v1 = 0.f;
#pragma unroll
    for (int e = 0; e < 8; ++e) {
      if (e == i0) continue;
      if (i1 < 0 || noisy[e] > v1) { v1 = noisy[e]; i1 = e; }
    }
    float e1 = expf(v1 - v0);        // v0 >= v1
    float w0 = 1.f / (1.f + e1);
    float w1 = e1 * w0;
    tok_e[t * 2 + 0] = i0; tok_e[t * 2 + 1] = i1;
    tok_w[t * 2 + 0] = w0; tok_w[t * 2 + 1] = w1;
    atomicAdd(&counts[i0], 1);
    atomicAdd(&counts[i1], 1);
  }
}

// ---------------- scan: offsets + BOTH tile tables (1 thread, trivial; r6-verified pattern) ----------------
__global__ void scan_kernel(const int* __restrict__ counts, int* __restrict__ offsets,
                            int* __restrict__ cursor, int4* __restrict__ tiles,
                            int* __restrict__ ntiles, int4* __restrict__ tiles256,
                            int* __restrict__ nt256) {
  if (threadIdx.x == 0 && blockIdx.x == 0) {
    int off = 0, nt = 0, n2 = 0;
    for (int e = 0; e < E_EXP; ++e) {
      offsets[e] = off;
      int c = counts[e];
      for (int r = 0; r < c; r += BM) {
        tiles[nt] = make_int4(e, off + r, min(BM, c - r), 0);
        ++nt;
      }
      for (int r = 0; r < c; r += BM1) {
        tiles256[n2] = make_int4(e, off + r, min(BM1, c - r), 0);
        ++n2;
      }
      off += c;
      cursor[e] = 0;
    }
    offsets[E_EXP] = off;
    *ntiles = nt;
    *nt256 = n2;
  }
}

// ---------------- scatter tokens into compact per-expert pair lists ----------------
__global__ __launch_bounds__(256) void scatter_kernel(
    const int* __restrict__ tok_e, const float* __restrict__ tok_w,
    const int* __restrict__ offsets, int* __restrict__ cursor,
    int* __restrict__ pair_token, float* __restrict__ pair_w) {
  int t = blockIdx.x * 256 + threadIdx.x;
  if (t >= T_TOK) return;
#pragma unroll
  for (int k = 0; k < 2; ++k) {
    int e = tok_e[t * 2 + k];
    int pos = atomicAdd(&cursor[e], 1);
    int p = offsets[e] + pos;
    pair_token[p] = t;
    pair_w[p] = tok_w[t * 2 + k];
  }
}

// ---------------- FFN1: h = gelu(X_e @ W1_e + b1_e), grouped GEMM, bf16 MFMA ----------------
// r13: 256x128 tile, 512 threads / 8 waves (4M x 2N), wave-tile 64x64 --
// per-wave fragment/compute code BYTE-IDENTICAL to r8-verified; schedule is
// r8's counted-vmcnt depth-2 with 3 loads/stage. Staged bytes/FLOP -27%,
// B-panels read half as often, 16 waves/CU (2 blocks x 8 waves, 64KB LDS).
__global__ __launch_bounds__(512, 4) void ffn1_kernel(
    const unsigned short* __restrict__ xb,    // [T][D] bf16
    const unsigned short* __restrict__ w1t,   // [E][H][D] bf16 (transposed)
    const float* __restrict__ b1,             // [E][H]
    const int* __restrict__ pair_token,       // [TP]
    const int4* __restrict__ tiles256, const int* __restrict__ nt256,
    unsigned short* __restrict__ hbuf) {      // [TP][H] bf16
  const int NB = H_DIM / BN;                  // 32
  const int nwg = MAX_T256 * NB;              // 1536, %8==0
  int bid = blockIdx.x;
  int wg = (bid & 7) * (nwg >> 3) + (bid >> 3);   // bijective XCD chunking
  int tileId = wg / NB, nb = wg - tileId * NB;    // tile-major within an XCD
  if (tileId >= *nt256) return;
  int4 tl = tiles256[tileId];
  const int e = tl.x, row0 = tl.y, rows = tl.z;
  const int n0 = nb * BN;

  // 64KB LDS: staging As 2x16KB + Bs 2x8KB (48KB); epilogue reuses all 64KB
  __shared__ unsigned short sh[32768];
#define AS1(buf) (sh + (buf) * 8192)              // [256][32] shorts
#define BS1(buf) (sh + 16384 + (buf) * 4096)      // [128][32] shorts

  const int tid = threadIdx.x;
  const int wid = tid >> 6, lane = tid & 63;
  const int sr = tid >> 2;                    // staging row 0..127
  const int sc = tid & 3;                     // 16B chunk 0..3

  // A: 2 gload calls cover rows 0..127 / 128..255 (gathered); B: 1 call, rows 0..127
  int ra0 = row0 + sr;        if (ra0 > TP - 1) ra0 = TP - 1;
  int ra1 = row0 + sr + 128;  if (ra1 > TP - 1) ra1 = TP - 1;
  const unsigned short* a0 = xb + (size_t)pair_token[ra0] * D_DIM + SWZ(sr, sc) * 8;
  const unsigned short* a1 = xb + (size_t)pair_token[ra1] * D_DIM + SWZ(sr + 128, sc) * 8;
  const unsigned short* bp = w1t + ((size_t)e * H_DIM + (n0 + sr)) * D_DIM + SWZ(sr, sc) * 8;

  const int wbase = wid * 128;                // wave-uniform LDS offset (shorts): 64 lanes x 8 shorts... tid*8
  // NOTE: LDS dest offset = tid*8 shorts overall; per-wave base = wid*512 shorts for
  // the 4-thread/row layout (tid>>2 rows). For A second call add 128 rows = 4096 shorts.
  const int ldso = wid * 512;                 // = (wavebase>>2)*32; dest = base + lane*16B

  const int wr = wid >> 1, wc = wid & 1;      // 4M x 2N wave grid
  const int lrow = lane & 15, lkc = lane >> 4;

  f32x4 acc[4][4] = {};

  auto stage = [&](int buf, int k0) {         // exactly 3 VMEM ops per wave
    gload16(a0 + k0, AS1(buf) + ldso);
    gload16(a1 + k0, AS1(buf) + 4096 + ldso);
    gload16(bp + k0, BS1(buf) + ldso);
  };
  auto compute_step = [&](int buf) {          // byte-identical inner code to r8
    bf16x8 af[4], bfr[4];
#pragma unroll
    for (int m = 0; m < 4; ++m) {
      int r = wr * 64 + m * 16 + lrow;        // 0..255 (M)
      af[m] = *(const bf16x8*)(AS1(buf) + r * BKS + SWZ(r, lkc) * 8);
    }
#pragma unroll
    for (int n = 0; n < 4; ++n) {
      int r = wc * 64 + n * 16 + lrow;        // 0..127 (N)
      bfr[n] = *(const bf16x8*)(BS1(buf) + r * BKS + SWZ(r, lkc) * 8);
    }
#pragma unroll
    for (int m = 0; m < 4; ++m)
#pragma unroll
      for (int n = 0; n < 4; ++n)
        acc[m][n] = __builtin_amdgcn_mfma_f32_16x16x32_bf16(af[m], bfr[n], acc[m][n], 0, 0, 0);
  };

  const int NK = D_DIM / BKS;                 // 32
  stage(0, 0);
  stage(1, BKS);
  int cur = 0;
  for (int k = 0; k < NK - 1; ++k) {
    asm volatile("s_waitcnt vmcnt(3)" ::: "memory");  // cur's 3 loads done; next 3 in flight
    __builtin_amdgcn_s_barrier();
    __builtin_amdgcn_sched_barrier(0);        // pin ds_reads after barrier
    compute_step(cur);
    __builtin_amdgcn_sched_barrier(0);
    __builtin_amdgcn_s_barrier();             // all reads of buf[cur] retired
    if (k < NK - 2) stage(cur, (k + 2) * BKS);  // refill (uniform branch)
    cur ^= 1;
  }
  asm volatile("s_waitcnt vmcnt(0)" ::: "memory");
  __builtin_amdgcn_s_barrier();
  __builtin_amdgcn_sched_barrier(0);
  compute_step(cur);

  // ---- epilogue: gelu -> LDS [256][128] (chunk-XOR swizzled) -> coalesced stores ----
  __syncthreads();                            // everyone done reading staging LDS
#pragma unroll
  for (int n = 0; n < 4; ++n) {
    int cl = wc * 64 + n * 16 + lrow;         // local col 0..127
    float bias = b1[(size_t)e * H_DIM + n0 + cl];
    int chunk = cl >> 3, within = cl & 7;
#pragma unroll
    for (int m = 0; m < 4; ++m) {
#pragma unroll
      for (int j = 0; j < 4; ++j) {
        int rloc = wr * 64 + m * 16 + (lane >> 4) * 4 + j;   // 0..255
        float v = acc[m][n][j] + bias;
        sh[rloc * 128 + ((chunk ^ ((rloc >> 1) & 7)) * 8) + within] = f2bf(gelu_fast(v));
      }
    }
  }
  __syncthreads();
#pragma unroll
  for (int it = 0; it < 8; ++it) {
    int u = tid + 512 * it;                   // 0..4095: row = u>>4, 16B-chunk = u&15
    int r = u >> 4, cg = u & 15;
    if (r < rows) {
      u16x8 v = *(const u16x8*)(&sh[r * 128 + ((cg ^ ((r >> 1) & 7)) * 8)]);
      *(u16x8*)(&hbuf[(size_t)(row0 + r) * H_DIM + n0 + cg * 8]) = v;  // 256B runs/row
    }
  }
#undef AS1
#undef BS1
  (void)wbase;
}

// ---------------- FFN2: out[token] += w * (h_e @ W2_e + b2_e) ----------------
// r8/r10-verified kernel (BM=128, acc[4][4], counted vmcnt(4) depth-2 pipeline).
__global__ __launch_bounds__(256) void ffn2_kernel(
    const unsigned short* __restrict__ hbuf,  // [TP][H] bf16
    const unsigned short* __restrict__ w2t,   // [E][D][H] bf16 (transposed)
    const float* __restrict__ b2,             // [E][D]
    const int* __restrict__ pair_token, const float* __restrict__ pair_w,
    const int4* __restrict__ tiles, const int* __restrict__ ntiles,
    float* __restrict__ out) {
  const int NB = D_DIM / BN;                  // 8
  const int nwg = MAX_TILES * NB;             // 576, %8==0
  int bid = blockIdx.x;
  int wg = (bid & 7) * (nwg >> 3) + (bid >> 3);
  int tileId = wg / NB, nb = wg - tileId * NB;
  if (tileId >= *ntiles) return;
  int4 tl = tiles[tileId];
  const int e = tl.x, row0 = tl.y, rows = tl.z;
  const int n0 = nb * BN;

  __shared__ unsigned short As[2][BM * BKS];
  __shared__ unsigned short Bs[2][BN * BKS];
  __shared__ int stok[BM];
  __shared__ float spw[BM];

  const int tid = threadIdx.x;
  if (tid < BM) {
    int rr = row0 + tid; if (rr > TP - 1) rr = TP - 1;
    stok[tid] = pair_token[rr];
    spw[tid] = pair_w[rr];
  }

  const int wid = tid >> 6, lane = tid & 63;
  const int sr = tid >> 2;
  const int sc = tid & 3;
  const int scz = SWZ(sr, sc) * 8;

  int r0a = row0 + sr;       if (r0a > TP - 1) r0a = TP - 1;
  int r1a = row0 + sr + 64;  if (r1a > TP - 1) r1a = TP - 1;
  const unsigned short* a0 = hbuf + (size_t)r0a * H_DIM + scz;
  const unsigned short* a1 = hbuf + (size_t)r1a * H_DIM + scz;
  const unsigned short* bp0 = w2t + ((size_t)e * D_DIM + (n0 + sr)) * H_DIM + scz;
  const unsigned short* bp1 = w2t + ((size_t)e * D_DIM + (n0 + sr + 64)) * H_DIM + scz;

  const int wbase = wid * 512;
  const int wr = wid >> 1, wc = wid & 1;
  const int lrow = lane & 15, lkc = lane >> 4;

  f32x4 acc[4][4] = {};

  auto stage = [&](int buf, int k0) {
    gload16(a0 + k0, &As[buf][wbase]);
    gload16(a1 + k0, &As[buf][wbase + 2048]);
    gload16(bp0 + k0, &Bs[buf][wbase]);
    gload16(bp1 + k0, &Bs[buf][wbase + 2048]);
  };
  auto compute_step = [&](int buf) {
    bf16x8 af[4], bfr[4];
#pragma unroll
    for (int m = 0; m < 4; ++m) {
      int r = wr * 64 + m * 16 + lrow;
      af[m] = *(const bf16x8*)(&As[buf][r * BKS + SWZ(r, lkc) * 8]);
    }
#pragma unroll
    for (int n = 0; n < 4; ++n) {
      int r = wc * 64 + n * 16 + lrow;
      bfr[n] = *(const bf16x8*)(&Bs[buf][r * BKS + SWZ(r, lkc) * 8]);
    }
#pragma unroll
    for (int m = 0; m < 4; ++m)
#pragma unroll
      for (int n = 0; n < 4; ++n)
        acc[m][n] = __builtin_amdgcn_mfma_f32_16x16x32_bf16(af[m], bfr[n], acc[m][n], 0, 0, 0);
  };

  const int NK = H_DIM / BKS;                 // 128
  stage(0, 0);
  stage(1, BKS);
  int cur = 0;
  for (int k = 0; k < NK - 1; ++k) {
    asm volatile("s_waitcnt vmcnt(4)" ::: "memory");
    __builtin_amdgcn_s_barrier();
    __builtin_amdgcn_sched_barrier(0);
    compute_step(cur);
    __builtin_amdgcn_sched_barrier(0);
    __builtin_amdgcn_s_barrier();
    if (k < NK - 2) stage(cur, (k + 2) * BKS);
    cur ^= 1;
  }
  asm volatile("s_waitcnt vmcnt(0)" ::: "memory");
  __builtin_amdgcn_s_barrier();
  __builtin_amdgcn_sched_barrier(0);
  compute_step(cur);

  const int colbase = n0 + wc * 64;
#pragma unroll
  for (int n = 0; n < 4; ++n) {
    int colg = colbase + n * 16 + lrow;
    float bias = b2[(size_t)e * D_DIM + colg];
#pragma unroll
    for (int m = 0; m < 4; ++m) {
      int rbase = wr * 64 + m * 16 + (lane >> 4) * 4;
#pragma unroll
      for (int j = 0; j < 4; ++j) {
        int rloc = rbase + j;
        if (rloc < rows) {
          float v = acc[m][n][j] + bias;
          // exactly 2 atomic adds per output element (one per selected expert);
          // fp32 add is commutative -> deterministic for 2 contributions
          unsafeAtomicAdd(&out[(size_t)stok[rloc] * D_DIM + colg], spw[rloc] * v);
        }
      }
    }
  }
}

// ---------------- load-balancing loss: deterministic fixed-order reduction ----------------
__global__ __launch_bounds__(256) void loss_kernel(
    const float* __restrict__ gp_tok, const int* __restrict__ counts,
    float* __restrict__ out) {
  __shared__ float red[256];
  const int tid = threadIdx.x;
  float part[8] = {0, 0, 0, 0, 0, 0, 0, 0};
  for (int r = tid; r < T_TOK; r += 256) {
    const float* g = gp_tok + (size_t)r * 8;
#pragma unroll
    for (int e = 0; e < 8; ++e) part[e] += g[e];
  }
  float total[8];
#pragma unroll
  for (int e = 0; e < 8; ++e) {
    red[tid] = part[e];
    __syncthreads();
    for (int s = 128; s > 0; s >>= 1) {
      if (tid < s) red[tid] += red[tid + s];
      __syncthreads();
    }
    if (tid == 0) total[e] = red[0];
    __syncthreads();
  }
  if (tid == 0) {
    float ll = 0.f;
#pragma unroll
    for (int e = 0; e < 8; ++e)
      ll += ((float)counts[e] / (float)TP) * (total[e] / (float)T_TOK);
    out[(size_t)T_TOK * D_DIM] = ll * (float)E_EXP;
  }
}

extern "C" void kernel_launch(void* const* d_in, const int* in_sizes, int n_in,
                              void* d_out, int out_size, void* d_ws, size_t ws_size,
                              hipStream_t stream) {
  (void)in_sizes; (void)n_in; (void)ws_size;
  const float* x     = (const float*)d_in[0];
  const float* noise = (const float*)d_in[1];
  const float* Wg    = (const float*)d_in[2];
  const float* bg    = (const float*)d_in[3];
  const float* Wn    = (const float*)d_in[4];
  const float* bn    = (const float*)d_in[5];
  const float* W1    = (const float*)d_in[6];
  const float* b1    = (const float*)d_in[7];
  const float* W2    = (const float*)d_in[8];
  const float* b2    = (const float*)d_in[9];
  float* out = (float*)d_out;

  char* ws = (char*)d_ws;
  size_t o = 0;
  auto take = [&](size_t b) { size_t r = o; o += (b + 255) & ~(size_t)255; return r; };
  int*   counts     = (int*)(ws + take(16 * 4));        // counts[8] + cursor[8], zeroed
  int*   cursor     = counts + 8;
  int*   offsets    = (int*)(ws + take(9 * 4));
  int*   ntiles     = (int*)(ws + take(4));
  int*   nt256      = (int*)(ws + take(4));
  int4*  tiles      = (int4*)(ws + take(MAX_TILES * 16));
  int4*  tiles256   = (int4*)(ws + take(MAX_T256 * 16));
  int*   tok_e      = (int*)(ws + take((size_t)TP * 4));
  float* tok_w      = (float*)(ws + take((size_t)TP * 4));
  float* gp_tok     = (float*)(ws + take((size_t)T_TOK * 8 * 4));
  int*   pair_token = (int*)(ws + take((size_t)TP * 4));
  float* pair_w     = (float*)(ws + take((size_t)TP * 4));
  unsigned short* xb  = (unsigned short*)(ws + take((size_t)T_TOK * D_DIM * 2));
  unsigned short* w1t = (unsigned short*)(ws + take((size_t)E_EXP * H_DIM * D_DIM * 2));
  unsigned short* w2t = (unsigned short*)(ws + take((size_t)E_EXP * H_DIM * D_DIM * 2));
  unsigned short* hbuf = (unsigned short*)(ws + take((size_t)TP * H_DIM * 2));
  // total ws usage ~201 MB

  hipMemsetAsync(d_out, 0, (size_t)out_size * sizeof(float), stream);
  hipMemsetAsync(counts, 0, 16 * 4, stream);

  transpose_bf16_kernel<<<dim3(H_DIM / 64, D_DIM / 64, E_EXP), 256, 0, stream>>>(
      W1, w1t, D_DIM, H_DIM);
  transpose_bf16_kernel<<<dim3(D_DIM / 64, H_DIM / 64, E_EXP), 256, 0, stream>>>(
      W2, w2t, H_DIM, D_DIM);
  gating_kernel<<<T_TOK / 4, 256, 0, stream>>>(x, noise, Wg, bg, Wn, bn,
                                               tok_e, tok_w, gp_tok, counts, xb);
  scan_kernel<<<1, 64, 0, stream>>>(counts, offsets, cursor, tiles, ntiles,
                                    tiles256, nt256);
  scatter_kernel<<<T_TOK / 256, 256, 0, stream>>>(tok_e, tok_w, offsets, cursor,
                                                  pair_token, pair_w);
  ffn1_kernel<<<dim3(MAX_T256 * (H_DIM / BN)), 512, 0, stream>>>(
      xb, w1t, b1, pair_token, tiles256, nt256, hbuf);
  ffn2_kernel<<<dim3(MAX_TILES * (D_DIM / BN)), 256, 0, stream>>>(
      hbuf, w2t, b2, pair_token, pair_w, tiles, ntiles, out);
  loss_kernel<<<1, 256, 0, stream>>>(gp_tok, counts, out);
}

// Round 14
// 437.159 us; speedup vs baseline: 1.2906x; 1.1412x over previous
//
#include <hip/hip_runtime.h>
#include <hip/hip_bf16.h>

// Problem constants
#define T_TOK 4096          // B*S tokens
#define D_DIM 1024
#define H_DIM 4096
#define E_EXP 8
#define K_TOP 2
#define TP (T_TOK * K_TOP)  // 8192 (token, expert) pairs
#define BM 128
#define BN 128
#define BKS 32              // K-step (shorts) -- r2/r5-verified
#define MAX_TILES 72

typedef __attribute__((ext_vector_type(8))) short bf16x8;
typedef __attribute__((ext_vector_type(4))) float f32x4;
typedef __attribute__((ext_vector_type(8))) unsigned short u16x8;
typedef __attribute__((ext_vector_type(4))) unsigned short u16x4;

// LDS chunk swizzle: permute the four 16B chunks within a row's 64B slab.
// Verified r2/r5/r6/r8/r10: SQ_LDS_BANK_CONFLICT == 0.
#define SWZ(row, chunk) ((chunk) ^ (((row) >> 1) & 3))

static __device__ __forceinline__ void gload16(const unsigned short* g, unsigned short* l) {
  // async global->LDS, 16B per lane; LDS dest = wave-uniform base + lane*16
  __builtin_amdgcn_global_load_lds((const __attribute__((address_space(1))) void*)g,
                                   (__attribute__((address_space(3))) void*)l, 16, 0, 0);
}

static __device__ __forceinline__ unsigned short f2bf(float f) {
  // round-to-nearest-even fp32 -> bf16
  unsigned int bits = __float_as_uint(f);
  unsigned int lsb = (bits >> 16) & 1u;
  bits += 0x7fffu + lsb;
  return (unsigned short)(bits >> 16);
}

static __device__ __forceinline__ float gelu_fast(float u) {
  // tanh-form gelu: u * sigmoid(1.5957691 * (u + 0.044715 u^3)); |err| <~ 3e-4
  float z = u * (0.79788456080286536f + 0.0356774081f * u * u);
  float t = __expf(-2.f * z);
  return u / (1.f + t);
}

// =====================================================================
// FRONT: fused {gating (blocks 0..1023)} + {W1 transpose} + {W2 transpose}.
// All independent; gating first so its latency hides under transpose BW.
// Bodies byte-identical to the r10-verified kernels.
// =====================================================================
#define NGATE (T_TOK / 4)                    // 1024
#define NTR1  ((H_DIM / 64) * (D_DIM / 64) * E_EXP)   // 8192
#define NTR2  ((D_DIM / 64) * (H_DIM / 64) * E_EXP)   // 8192

__global__ __launch_bounds__(256) void front_kernel(
    const float* __restrict__ W1, unsigned short* __restrict__ w1t,
    const float* __restrict__ W2, unsigned short* __restrict__ w2t,
    const float* __restrict__ x, const float* __restrict__ noise,
    const float* __restrict__ Wg, const float* __restrict__ bg,
    const float* __restrict__ Wn, const float* __restrict__ bn,
    int* __restrict__ tok_e, float* __restrict__ tok_w,
    float* __restrict__ gp_tok, int* __restrict__ counts,
    unsigned short* __restrict__ xb) {
  __shared__ float tile[64][65];             // used by transpose paths only
  int bid = blockIdx.x;
  const int tid = threadIdx.x;

  if (bid < NGATE) {
    // ---------------- gating body (r9/r10-verified) ----------------
    const int lane = tid & 63, wid = tid >> 6;
    const int t = bid * 4 + wid;
    const float* xrow = x + (size_t)t * D_DIM;
    float ag[8] = {0, 0, 0, 0, 0, 0, 0, 0};
    float an[8] = {0, 0, 0, 0, 0, 0, 0, 0};
#pragma unroll 4
    for (int i = 0; i < 16; ++i) {
      int dd = i * 64 + lane;
      float xv = xrow[dd];
      xb[(size_t)t * D_DIM + dd] = f2bf(xv);        // fused x -> bf16
      const float4* g4 = (const float4*)(Wg + (size_t)dd * 8);
      const float4* n4 = (const float4*)(Wn + (size_t)dd * 8);
      float4 ga = g4[0], gb = g4[1], na = n4[0], nb = n4[1];
      ag[0] += xv * ga.x; ag[1] += xv * ga.y; ag[2] += xv * ga.z; ag[3] += xv * ga.w;
      ag[4] += xv * gb.x; ag[5] += xv * gb.y; ag[6] += xv * gb.z; ag[7] += xv * gb.w;
      an[0] += xv * na.x; an[1] += xv * na.y; an[2] += xv * na.z; an[3] += xv * na.w;
      an[4] += xv * nb.x; an[5] += xv * nb.y; an[6] += xv * nb.z; an[7] += xv * nb.w;
    }
#pragma unroll
    for (int e = 0; e < 8; ++e) {
      for (int off = 32; off > 0; off >>= 1) {
        ag[e] += __shfl_down(ag[e], off);
        an[e] += __shfl_down(an[e], off);
      }
    }
    if (lane == 0) {
      float logit[8], noisy[8];
#pragma unroll
      for (int e = 0; e < 8; ++e) {
        logit[e] = ag[e] + bg[e];
        float pre = an[e] + bn[e];
        float sp = fmaxf(pre, 0.f) + log1pf(expf(-fabsf(pre)));   // softplus, stable
        noisy[e] = logit[e] + noise[(size_t)t * 8 + e] * sp;
      }
      float mx = logit[0];
#pragma unroll
      for (int e = 1; e < 8; ++e) mx = fmaxf(mx, logit[e]);
      float s = 0.f, p[8];
#pragma unroll
      for (int e = 0; e < 8; ++e) { p[e] = expf(logit[e] - mx); s += p[e]; }
      float inv = 1.f / s;
#pragma unroll
      for (int e = 0; e < 8; ++e) gp_tok[(size_t)t * 8 + e] = p[e] * inv;
      // top-2 (strict > keeps lowest index on ties, matching lax.top_k)
      int i0 = 0; float v0 = noisy[0];
#pragma unroll
      for (int e = 1; e < 8; ++e) if (noisy[e] > v0) { v0 = noisy[e]; i0 = e; }
      int i1 = -1; float v1 = 0.f;
#pragma unroll
      for (int e = 0; e < 8; ++e) {
        if (e == i0) continue;
        if (i1 < 0 || noisy[e] > v1) { v1 = noisy[e]; i1 = e; }
      }
      float e1 = expf(v1 - v0);      // v0 >= v1
      float w0 = 1.f / (1.f + e1);
      float w1 = e1 * w0;
      tok_e[t * 2 + 0] = i0; tok_e[t * 2 + 1] = i1;
      tok_w[t * 2 + 0] = w0; tok_w[t * 2 + 1] = w1;
      atomicAdd(&counts[i0], 1);
      atomicAdd(&counts[i1], 1);
    }
    return;
  }
  bid -= NGATE;

  // ---------------- transpose body (r8-verified), two sources ----------------
  const float* src; unsigned short* dst; int R, C, bx, by, e;
  if (bid < NTR1) {                          // W1: [E][D][H] -> [E][H][D]
    R = D_DIM; C = H_DIM;
    bx = bid & 63; by = (bid >> 6) & 15; e = bid >> 10;
    src = W1; dst = w1t;
  } else {                                   // W2: [E][H][D] -> [E][D][H]
    bid -= NTR1;
    R = H_DIM; C = D_DIM;
    bx = bid & 15; by = (bid >> 4) & 63; e = bid >> 10;
    src = W2; dst = w2t;
  }
  const int c0 = bx * 64, r0 = by * 64;
  const float* s = src + (size_t)e * R * C;
  unsigned short* d = dst + (size_t)e * R * C;

  const int rr = tid >> 4, c4 = tid & 15;
#pragma unroll
  for (int p = 0; p < 4; ++p) {
    int r = rr + p * 16;
    float4 v = *(const float4*)(&s[(size_t)(r0 + r) * C + c0 + c4 * 4]);
    tile[r][c4 * 4 + 0] = v.x;
    tile[r][c4 * 4 + 1] = v.y;
    tile[r][c4 * 4 + 2] = v.z;
    tile[r][c4 * 4 + 3] = v.w;
  }
  __syncthreads();
  const int cc = tid >> 3, r8 = tid & 7;
#pragma unroll
  for (int p = 0; p < 2; ++p) {
    int c = cc + p * 32;
    u16x8 o;
#pragma unroll
    for (int q = 0; q < 8; ++q) o[q] = f2bf(tile[r8 * 8 + q][c]);
    *(u16x8*)(&d[(size_t)(c0 + c) * R + r0 + r8 * 8]) = o;
  }
}

// =====================================================================
// FINALIZE: fused scan + scatter (LDS cursors) + load-balancing loss.
// One block, 256 threads. Scatter order within an expert is arbitrary
// (each pair carries its token+weight; fp32 atomic adds commute).
// =====================================================================
__global__ __launch_bounds__(256) void finalize_kernel(
    const int* __restrict__ counts, int4* __restrict__ tiles,
    int* __restrict__ ntiles,
    const int* __restrict__ tok_e, const float* __restrict__ tok_w,
    int* __restrict__ pair_token, float* __restrict__ pair_w,
    const float* __restrict__ gp_tok, float* __restrict__ out) {
  __shared__ int s_off[E_EXP];
  __shared__ int s_cur[E_EXP];
  __shared__ float red[256];
  const int tid = threadIdx.x;

  if (tid == 0) {
    int off = 0, nt = 0;
    for (int e = 0; e < E_EXP; ++e) {
      s_off[e] = off;
      int c = counts[e];
      for (int r = 0; r < c; r += BM) {
        tiles[nt] = make_int4(e, off + r, min(BM, c - r), 0);
        ++nt;
      }
      off += c;
    }
    *ntiles = nt;
  }
  if (tid < E_EXP) s_cur[tid] = 0;
  __syncthreads();

  // scatter: 4096 tokens / 256 threads = 16 iters; cursors in LDS
  for (int t = tid; t < T_TOK; t += 256) {
#pragma unroll
    for (int k = 0; k < 2; ++k) {
      int e = tok_e[t * 2 + k];
      int pos = atomicAdd(&s_cur[e], 1);
      int p = s_off[e] + pos;
      pair_token[p] = t;
      pair_w[p] = tok_w[t * 2 + k];
    }
  }

  // loss: deterministic fixed-order reduction (r10-verified body)
  float part[8] = {0, 0, 0, 0, 0, 0, 0, 0};
  for (int r = tid; r < T_TOK; r += 256) {
    const float* g = gp_tok + (size_t)r * 8;
#pragma unroll
    for (int e = 0; e < 8; ++e) part[e] += g[e];
  }
  float total[8];
#pragma unroll
  for (int e = 0; e < 8; ++e) {
    red[tid] = part[e];
    __syncthreads();
    for (int s = 128; s > 0; s >>= 1) {
      if (tid < s) red[tid] += red[tid + s];
      __syncthreads();
    }
    if (tid == 0) total[e] = red[0];
    __syncthreads();
  }
  if (tid == 0) {
    float ll = 0.f;
#pragma unroll
    for (int e = 0; e < 8; ++e)
      ll += ((float)counts[e] / (float)TP) * (total[e] / (float)T_TOK);
    out[(size_t)T_TOK * D_DIM] = ll * (float)E_EXP;
  }
}

// ---------------- FFN1: h = gelu(X_e @ W1_e + b1_e), grouped GEMM, bf16 MFMA ----------------
// r6/r8/r10-verified: counted vmcnt(4) depth-2 pipeline + coalesced LDS epilogue.
__global__ __launch_bounds__(256) void ffn1_kernel(
    const unsigned short* __restrict__ xb,    // [T][D] bf16
    const unsigned short* __restrict__ w1t,   // [E][H][D] bf16 (transposed)
    const float* __restrict__ b1,             // [E][H]
    const int* __restrict__ pair_token,       // [TP]
    const int4* __restrict__ tiles, const int* __restrict__ ntiles,
    unsigned short* __restrict__ hbuf) {      // [TP][H] bf16
  const int NB = H_DIM / BN;                  // 32
  const int nwg = MAX_TILES * NB;             // 2304, %8==0
  int bid = blockIdx.x;
  int wg = (bid & 7) * (nwg >> 3) + (bid >> 3);   // bijective XCD chunking
  int tileId = wg / NB, nb = wg - tileId * NB;    // tile-major within an XCD
  if (tileId >= *ntiles) return;
  int4 tl = tiles[tileId];
  const int e = tl.x, row0 = tl.y, rows = tl.z;
  const int n0 = nb * BN;

  __shared__ unsigned short sh[16384];        // 32KB: As(2x8KB)+Bs(2x8KB); reused as [128][128] epilogue tile
#define AS1(buf) (sh + (buf) * 4096)
#define BS1(buf) (sh + 8192 + (buf) * 4096)

  const int tid = threadIdx.x;
  const int wid = tid >> 6, lane = tid & 63;
  const int sr = tid >> 2;                    // local row 0..63 (and +64)
  const int sc = tid & 3;                     // 16B chunk 0..3
  const int scz = SWZ(sr, sc) * 8;            // swizzled source column (shorts)

  int r0a = row0 + sr;       if (r0a > TP - 1) r0a = TP - 1;
  int r1a = row0 + sr + 64;  if (r1a > TP - 1) r1a = TP - 1;
  const unsigned short* a0 = xb + (size_t)pair_token[r0a] * D_DIM + scz;
  const unsigned short* a1 = xb + (size_t)pair_token[r1a] * D_DIM + scz;
  const unsigned short* bp0 = w1t + ((size_t)e * H_DIM + (n0 + sr)) * D_DIM + scz;
  const unsigned short* bp1 = w1t + ((size_t)e * H_DIM + (n0 + sr + 64)) * D_DIM + scz;

  const int wbase = wid * 512;                // wave-uniform LDS offset (shorts)
  const int wr = wid >> 1, wc = wid & 1;
  const int lrow = lane & 15, lkc = lane >> 4;  // fragment chunk 0..3

  f32x4 acc[4][4] = {};

  auto stage = [&](int buf, int k0) {         // exactly 4 VMEM ops per wave
    gload16(a0 + k0, AS1(buf) + wbase);
    gload16(a1 + k0, AS1(buf) + wbase + 2048);
    gload16(bp0 + k0, BS1(buf) + wbase);
    gload16(bp1 + k0, BS1(buf) + wbase + 2048);
  };
  auto compute_step = [&](int buf) {
    bf16x8 af[4], bfr[4];
#pragma unroll
    for (int m = 0; m < 4; ++m) {
      int r = wr * 64 + m * 16 + lrow;
      af[m] = *(const bf16x8*)(AS1(buf) + r * BKS + SWZ(r, lkc) * 8);
    }
#pragma unroll
    for (int n = 0; n < 4; ++n) {
      int r = wc * 64 + n * 16 + lrow;
      bfr[n] = *(const bf16x8*)(BS1(buf) + r * BKS + SWZ(r, lkc) * 8);
    }
#pragma unroll
    for (int m = 0; m < 4; ++m)
#pragma unroll
      for (int n = 0; n < 4; ++n)
        acc[m][n] = __builtin_amdgcn_mfma_f32_16x16x32_bf16(af[m], bfr[n], acc[m][n], 0, 0, 0);
  };

  const int NK = D_DIM / BKS;                 // 32
  stage(0, 0);
  stage(1, BKS);
  int cur = 0;
  for (int k = 0; k < NK - 1; ++k) {
    asm volatile("s_waitcnt vmcnt(4)" ::: "memory");  // cur's 4 loads done; next 4 in flight
    __builtin_amdgcn_s_barrier();
    __builtin_amdgcn_sched_barrier(0);        // pin ds_reads after barrier
    compute_step(cur);
    __builtin_amdgcn_sched_barrier(0);
    __builtin_amdgcn_s_barrier();             // all reads of buf[cur] retired
    if (k < NK - 2) stage(cur, (k + 2) * BKS);  // refill (uniform branch)
    cur ^= 1;
  }
  asm volatile("s_waitcnt vmcnt(0)" ::: "memory");
  __builtin_amdgcn_s_barrier();
  __builtin_amdgcn_sched_barrier(0);
  compute_step(cur);

  // ---- epilogue: gelu -> LDS [128][128] (chunk-XOR swizzled) -> coalesced stores ----
  __syncthreads();                            // everyone done reading staging LDS
#pragma unroll
  for (int n = 0; n < 4; ++n) {
    int clocal = wc * 64 + n * 16 + lrow;
    float bias = b1[(size_t)e * H_DIM + n0 + clocal];
    int chunk = clocal >> 3, within = clocal & 7;
#pragma unroll
    for (int m = 0; m < 4; ++m) {
#pragma unroll
      for (int j = 0; j < 4; ++j) {
        int rloc = wr * 64 + m * 16 + (lane >> 4) * 4 + j;
        float v = acc[m][n][j] + bias;
        sh[rloc * 128 + ((chunk ^ ((rloc >> 1) & 7)) * 8) + within] = f2bf(gelu_fast(v));
      }
    }
  }
  __syncthreads();
#pragma unroll
  for (int it = 0; it < 8; ++it) {
    int u = tid + 256 * it;                   // 0..2047: row = u>>4, 16B-chunk = u&15
    int r = u >> 4, cg = u & 15;
    if (r < rows) {
      u16x8 v = *(const u16x8*)(&sh[r * 128 + ((cg ^ ((r >> 1) & 7)) * 8)]);
      *(u16x8*)(&hbuf[(size_t)(row0 + r) * H_DIM + n0 + cg * 8]) = v;  // 256B runs/row
    }
  }
#undef AS1
#undef BS1
}

// ---------------- FFN2: out[token] += w * (h_e @ W2_e + b2_e) ----------------
// r8/r10-verified kernel (BM=128, acc[4][4], counted vmcnt(4) depth-2 pipeline).
__global__ __launch_bounds__(256) void ffn2_kernel(
    const unsigned short* __restrict__ hbuf,  // [TP][H] bf16
    const unsigned short* __restrict__ w2t,   // [E][D][H] bf16 (transposed)
    const float* __restrict__ b2,             // [E][D]
    const int* __restrict__ pair_token, const float* __restrict__ pair_w,
    const int4* __restrict__ tiles, const int* __restrict__ ntiles,
    float* __restrict__ out) {
  const int NB = D_DIM / BN;                  // 8
  const int nwg = MAX_TILES * NB;             // 576, %8==0
  int bid = blockIdx.x;
  int wg = (bid & 7) * (nwg >> 3) + (bid >> 3);
  int tileId = wg / NB, nb = wg - tileId * NB;
  if (tileId >= *ntiles) return;
  int4 tl = tiles[tileId];
  const int e = tl.x, row0 = tl.y, rows = tl.z;
  const int n0 = nb * BN;

  __shared__ unsigned short As[2][BM * BKS];
  __shared__ unsigned short Bs[2][BN * BKS];
  __shared__ int stok[BM];
  __shared__ float spw[BM];

  const int tid = threadIdx.x;
  if (tid < BM) {
    int rr = row0 + tid; if (rr > TP - 1) rr = TP - 1;
    stok[tid] = pair_token[rr];
    spw[tid] = pair_w[rr];
  }

  const int wid = tid >> 6, lane = tid & 63;
  const int sr = tid >> 2;
  const int sc = tid & 3;
  const int scz = SWZ(sr, sc) * 8;

  int r0a = row0 + sr;       if (r0a > TP - 1) r0a = TP - 1;
  int r1a = row0 + sr + 64;  if (r1a > TP - 1) r1a = TP - 1;
  const unsigned short* a0 = hbuf + (size_t)r0a * H_DIM + scz;
  const unsigned short* a1 = hbuf + (size_t)r1a * H_DIM + scz;
  const unsigned short* bp0 = w2t + ((size_t)e * D_DIM + (n0 + sr)) * H_DIM + scz;
  const unsigned short* bp1 = w2t + ((size_t)e * D_DIM + (n0 + sr + 64)) * H_DIM + scz;

  const int wbase = wid * 512;
  const int wr = wid >> 1, wc = wid & 1;
  const int lrow = lane & 15, lkc = lane >> 4;

  f32x4 acc[4][4] = {};

  auto stage = [&](int buf, int k0) {
    gload16(a0 + k0, &As[buf][wbase]);
    gload16(a1 + k0, &As[buf][wbase + 2048]);
    gload16(bp0 + k0, &Bs[buf][wbase]);
    gload16(bp1 + k0, &Bs[buf][wbase + 2048]);
  };
  auto compute_step = [&](int buf) {
    bf16x8 af[4], bfr[4];
#pragma unroll
    for (int m = 0; m < 4; ++m) {
      int r = wr * 64 + m * 16 + lrow;
      af[m] = *(const bf16x8*)(&As[buf][r * BKS + SWZ(r, lkc) * 8]);
    }
#pragma unroll
    for (int n = 0; n < 4; ++n) {
      int r = wc * 64 + n * 16 + lrow;
      bfr[n] = *(const bf16x8*)(&Bs[buf][r * BKS + SWZ(r, lkc) * 8]);
    }
#pragma unroll
    for (int m = 0; m < 4; ++m)
#pragma unroll
      for (int n = 0; n < 4; ++n)
        acc[m][n] = __builtin_amdgcn_mfma_f32_16x16x32_bf16(af[m], bfr[n], acc[m][n], 0, 0, 0);
  };

  const int NK = H_DIM / BKS;                 // 128
  stage(0, 0);
  stage(1, BKS);
  int cur = 0;
  for (int k = 0; k < NK - 1; ++k) {
    asm volatile("s_waitcnt vmcnt(4)" ::: "memory");
    __builtin_amdgcn_s_barrier();
    __builtin_amdgcn_sched_barrier(0);
    compute_step(cur);
    __builtin_amdgcn_sched_barrier(0);
    __builtin_amdgcn_s_barrier();
    if (k < NK - 2) stage(cur, (k + 2) * BKS);
    cur ^= 1;
  }
  asm volatile("s_waitcnt vmcnt(0)" ::: "memory");
  __builtin_amdgcn_s_barrier();
  __builtin_amdgcn_sched_barrier(0);
  compute_step(cur);

  const int colbase = n0 + wc * 64;
#pragma unroll
  for (int n = 0; n < 4; ++n) {
    int colg = colbase + n * 16 + lrow;
    float bias = b2[(size_t)e * D_DIM + colg];
#pragma unroll
    for (int m = 0; m < 4; ++m) {
      int rbase = wr * 64 + m * 16 + (lane >> 4) * 4;
#pragma unroll
      for (int j = 0; j < 4; ++j) {
        int rloc = rbase + j;
        if (rloc < rows) {
          float v = acc[m][n][j] + bias;
          // exactly 2 atomic adds per output element (one per selected expert);
          // fp32 add is commutative -> deterministic for 2 contributions
          unsafeAtomicAdd(&out[(size_t)stok[rloc] * D_DIM + colg], spw[rloc] * v);
        }
      }
    }
  }
}

extern "C" void kernel_launch(void* const* d_in, const int* in_sizes, int n_in,
                              void* d_out, int out_size, void* d_ws, size_t ws_size,
                              hipStream_t stream) {
  (void)in_sizes; (void)n_in; (void)ws_size;
  const float* x     = (const float*)d_in[0];
  const float* noise = (const float*)d_in[1];
  const float* Wg    = (const float*)d_in[2];
  const float* bg    = (const float*)d_in[3];
  const float* Wn    = (const float*)d_in[4];
  const float* bn    = (const float*)d_in[5];
  const float* W1    = (const float*)d_in[6];
  const float* b1    = (const float*)d_in[7];
  const float* W2    = (const float*)d_in[8];
  const float* b2    = (const float*)d_in[9];
  float* out = (float*)d_out;

  char* ws = (char*)d_ws;
  size_t o = 0;
  auto take = [&](size_t b) { size_t r = o; o += (b + 255) & ~(size_t)255; return r; };
  int*   counts     = (int*)(ws + take(16 * 4));        // counts[8], zeroed
  int*   ntiles     = (int*)(ws + take(4));
  int4*  tiles      = (int4*)(ws + take(MAX_TILES * 16));
  int*   tok_e      = (int*)(ws + take((size_t)TP * 4));
  float* tok_w      = (float*)(ws + take((size_t)TP * 4));
  float* gp_tok     = (float*)(ws + take((size_t)T_TOK * 8 * 4));
  int*   pair_token = (int*)(ws + take((size_t)TP * 4));
  float* pair_w     = (float*)(ws + take((size_t)TP * 4));
  unsigned short* xb  = (unsigned short*)(ws + take((size_t)T_TOK * D_DIM * 2));
  unsigned short* w1t = (unsigned short*)(ws + take((size_t)E_EXP * H_DIM * D_DIM * 2));
  unsigned short* w2t = (unsigned short*)(ws + take((size_t)E_EXP * H_DIM * D_DIM * 2));
  unsigned short* hbuf = (unsigned short*)(ws + take((size_t)TP * H_DIM * 2));
  // total ws usage ~201 MB

  hipMemsetAsync(d_out, 0, (size_t)out_size * sizeof(float), stream);
  hipMemsetAsync(counts, 0, 16 * 4, stream);

  front_kernel<<<NGATE + NTR1 + NTR2, 256, 0, stream>>>(
      W1, w1t, W2, w2t, x, noise, Wg, bg, Wn, bn,
      tok_e, tok_w, gp_tok, counts, xb);
  finalize_kernel<<<1, 256, 0, stream>>>(counts, tiles, ntiles, tok_e, tok_w,
                                         pair_token, pair_w, gp_tok, out);
  ffn1_kernel<<<dim3(MAX_TILES * (H_DIM / BN)), 256, 0, stream>>>(
      xb, w1t, b1, pair_token, tiles, ntiles, hbuf);
  ffn2_kernel<<<dim3(MAX_TILES * (D_DIM / BN)), 256, 0, stream>>>(
      hbuf, w2t, b2, pair_token, pair_w, tiles, ntiles, out);
}